// Round 11
// baseline (310.771 us; speedup 1.0000x reference)
//
#include <hip/hip_runtime.h>
#include <cstdint>
#include <cstddef>

#define NN 20000
#define CAP 96

typedef __bf16 bf16_t;
typedef __bf16 bf16x8 __attribute__((ext_vector_type(8)));
typedef float f32x4 __attribute__((ext_vector_type(4)));

#define AS1 __attribute__((address_space(1)))
#define AS3 __attribute__((address_space(3)))

__device__ __forceinline__ float lrelu(float x) { return x >= 0.f ? x : 0.2f * x; }
__device__ __forceinline__ float bflo(uint32_t u) { return __uint_as_float(u << 16); }
__device__ __forceinline__ float bfhi(uint32_t u) { return __uint_as_float(u & 0xffff0000u); }

__device__ __forceinline__ uint32_t pack2bf(float a, float b) {
  bf16_t x = (bf16_t)a, y = (bf16_t)b;
  uint16_t ux = __builtin_bit_cast(uint16_t, x);
  uint16_t uy = __builtin_bit_cast(uint16_t, y);
  return (uint32_t)ux | ((uint32_t)uy << 16);
}

// ---------------- prep mega-kernel ----------------
// block ranges: [0,204) wprep | [204,716) alpha_proj | [716,780) merge_w3l1
//             | [780,780+EB) scatter
// NOTE: no block in this launch may READ an output produced by another block
// of this same launch (no intra-launch ordering). P1 consumers live in
// cast_alpha, a separate kernel.

struct WDesc { const float* W; bf16_t* Bt; int K; int Cw; int H; float scale; int b0; };
struct WPack { WDesc d[4]; };

struct Prep1Args {
  WPack wp;
  const float *W1, *as1, *ad1, *W2, *as2, *ad2, *W3, *as3, *ad3;
  float *P1, *P2, *P3;
  const float *W3m, *L1w, *b3v, *l1b;
  bf16_t* M3t; float* bm;
  const int* ei; int E, N, EB;
  int* cnt; int* col;
};

__global__ __launch_bounds__(256) void prep1(Prep1Args a) {
  __shared__ float tile[32][33];
  const int b = blockIdx.x;
  const int t = threadIdx.x;

  if (b < 204) {
    int i = 3;
#pragma unroll
    for (int k = 2; k >= 0; --k)
      if (b < a.wp.d[k + 1].b0) i = k;
    const WDesc de = a.wp.d[i];
    const int bi = b - de.b0;
    const int ktiles = de.K / 32;
    const int kt = bi % ktiles, rt = bi / ktiles;
    const int gc = rt * 32;
    const int h = gc / de.Cw, c0 = gc % de.Cw;
    const int tx = t & 31, ty = t >> 5;
#pragma unroll
    for (int r = 0; r < 32; r += 8)
      tile[ty + r][tx] = de.W[(size_t)(kt * 32 + ty + r) * (de.H * de.Cw) + h * de.Cw + c0 + tx];
    __syncthreads();
#pragma unroll
    for (int r = 0; r < 32; r += 8)
      de.Bt[(size_t)(c0 + ty + r) * (de.H * de.K) + h * de.K + kt * 32 + tx] =
          (bf16_t)(de.scale * tile[tx][ty + r]);
  } else if (b < 716) {
    const int kk = b - 204;
    const float *W, *asrc, *adst;
    float* P;
    int K, H, k;
    if (kk < 256)      { W = a.W1; asrc = a.as1; adst = a.ad1; P = a.P1; K = 256; H = 4; k = kk; }
    else if (kk < 384) { W = a.W2; asrc = a.as2; adst = a.ad2; P = a.P2; K = 128; H = 4; k = kk - 256; }
    else               { W = a.W3; asrc = a.as3; adst = a.ad3; P = a.P3; K = 128; H = 1; k = kk - 384; }
    for (int j = 0; j < 2 * H; ++j) {
      const int h = (j < H) ? j : j - H;
      const float* av = (j < H) ? asrc : adst;
      float pv = 0.f;
      if (t < 128) pv = W[(size_t)k * (H * 128) + h * 128 + t] * av[h * 128 + t];
#pragma unroll
      for (int d = 1; d < 64; d <<= 1) pv += __shfl_xor(pv, d);
      if (t == 0 || t == 64) tile[0][t >> 6] = pv;
      __syncthreads();
      if (t == 0) P[j * K + k] = tile[0][0] + tile[0][1];
      __syncthreads();
    }
  } else if (b < 780) {
    const int idx = (b - 716) * 256 + t;
    const int k = idx >> 7, c = idx & 127;
    float s = 0.f;
    for (int m = 0; m < 128; ++m) s += a.W3m[k * 128 + m] * a.L1w[m * 128 + c];
    a.M3t[c * 128 + k] = (bf16_t)s;
    if (k == 0) {
      float tt = a.l1b[c];
      for (int m = 0; m < 128; ++m) tt += a.b3v[m] * a.L1w[m * 128 + c];
      a.bm[c] = tt;
    }
  } else {
    // direct bucket scatter: replaces hist + scan + cursor-scatter
    const int i = (b - 780) * 256 + t;
    if (i < a.E + a.N) {
      int src, dst;
      if (i < a.E) { src = a.ei[i]; dst = a.ei[a.E + i]; }
      else         { src = i - a.E; dst = src; }
      int slot = atomicAdd(&a.cnt[dst], 1);
      a.col[(size_t)dst * CAP + slot] = src;
    }
  }
}

// ---------------- fused cast + layer-1 alpha (separate launch: consumes P1) ----------

__global__ __launch_bounds__(256) void cast_alpha(const float* __restrict__ x,
                                                  const float* __restrict__ P1,
                                                  bf16_t* __restrict__ xb,
                                                  float* __restrict__ asadA) {
  const int b = blockIdx.x, t = threadIdx.x;
  const int wv = t >> 6, lane = t & 63;
  const int n = b * 4 + wv;
  const float4 v = *(const float4*)&x[(size_t)n * 256 + lane * 4];
  uint2 ov;
  ov.x = pack2bf(v.x, v.y);
  ov.y = pack2bf(v.z, v.w);
  *(uint2*)&xb[(size_t)n * 256 + lane * 4] = ov;
  float s[8];
#pragma unroll
  for (int j = 0; j < 8; ++j) {
    const float4 pj = *(const float4*)&P1[j * 256 + lane * 4];
    s[j] = v.x * pj.x + v.y * pj.y + v.z * pj.z + v.w * pj.w;
  }
#pragma unroll
  for (int j = 0; j < 8; ++j)
#pragma unroll
    for (int d = 1; d < 64; d <<= 1) s[j] += __shfl_xor(s[j], d);
  if (lane == 0) {
#pragma unroll
    for (int j = 0; j < 8; ++j) asadA[(size_t)n * 8 + j] = s[j];
  }
}

// ---------------- bf16 MFMA GEMM: C = act(A @ Bt^T + bias) ----------------
// TM=32 x TN=128: 625 blocks (~2.4/CU). Used for layer 1 only now.
// ACT: 1=relu, 3=BN(eval)+relu
// J>0: fused alpha-logit epilogue: asad[r][j] += sum_c act(C[r][c]) * Pa[j*128+c]

template <int ACT, int J, typename OUT_T>
__global__ __launch_bounds__(256) void gemm_mfma(const bf16_t* __restrict__ A,
                                                 const bf16_t* __restrict__ Bt,
                                                 const float* __restrict__ bias,
                                                 const float* __restrict__ bng,
                                                 const float* __restrict__ bnb,
                                                 const float* __restrict__ bnm,
                                                 const float* __restrict__ bnv,
                                                 OUT_T* __restrict__ C,
                                                 const float* __restrict__ Pa,
                                                 float* __restrict__ asad,
                                                 int M, int N, int K) {
  constexpr int TM = 32, TN = 128, BK = 64;
  constexpr int NRA = (TM * BK * 2) / 4096;  // 1
  constexpr int NRB = (TN * BK * 2) / 4096;  // 4
  __shared__ __align__(16) bf16_t As[TM * BK];
  __shared__ __align__(16) bf16_t Bs[TN * BK];

  const int t = threadIdx.x;
  const int wave = t >> 6, lane = t & 63;
  const int ln15 = lane & 15, quad = lane >> 4;
  const int bm = blockIdx.x * TM;
  const int wm = (wave >> 1) * 16;   // 2 wave-rows x 16 rows
  const int wn = (wave & 1) * 64;    // 2 wave-cols x 64 cols
  const int rowLimA = M - 1 - bm;
  const size_t strideAB = (size_t)K * 2;

  f32x4 acc[4];
#pragma unroll
  for (int ni = 0; ni < 4; ++ni) acc[ni] = (f32x4){0.f, 0.f, 0.f, 0.f};

  const char* gA = (const char*)(A + (size_t)bm * K);
  const char* gB = (const char*)Bt;

  for (int k0 = 0; k0 < K; k0 += BK) {
#pragma unroll
    for (int r = 0; r < NRA; ++r) {
      int base = (wave * NRA + r) * 1024;
      int flat = base + lane * 16;
      int row = flat >> 7;
      int grow = row < rowLimA ? row : rowLimA;
      const char* gp = gA + (size_t)grow * strideAB + (size_t)(k0 * 2) + (flat & 127);
      __builtin_amdgcn_global_load_lds((const AS1 void*)gp,
                                       (AS3 void*)((char*)As + base), 16, 0, 0);
    }
#pragma unroll
    for (int r = 0; r < NRB; ++r) {
      int base = (wave * NRB + r) * 1024;
      int flat = base + lane * 16;
      int row = flat >> 7;
      const char* gp = gB + (size_t)row * strideAB + (size_t)(k0 * 2) + (flat & 127);
      __builtin_amdgcn_global_load_lds((const AS1 void*)gp,
                                       (AS3 void*)((char*)Bs + base), 16, 0, 0);
    }
    __syncthreads();
#pragma unroll
    for (int kk = 0; kk < BK; kk += 32) {
      bf16x8 af, bfr[4];
      af = *(const bf16x8*)&As[(wm + ln15) * BK + kk + quad * 8];
#pragma unroll
      for (int ni = 0; ni < 4; ++ni)
        bfr[ni] = *(const bf16x8*)&Bs[(wn + ni * 16 + ln15) * BK + kk + quad * 8];
#pragma unroll
      for (int ni = 0; ni < 4; ++ni)
        acc[ni] = __builtin_amdgcn_mfma_f32_16x16x32_bf16(af, bfr[ni], acc[ni], 0, 0, 0);
    }
    __syncthreads();
  }

  {
    int r0 = bm + wm + quad * 4;
#pragma unroll
    for (int ni = 0; ni < 4; ++ni) {
      int c = wn + ni * 16 + ln15;
      float bv = bias ? bias[c] : 0.f;
      float sc = 1.f, sh = 0.f;
      if (ACT == 3) {
        sc = bng[c] * rsqrtf(bnv[c] + 1e-5f);
        sh = bnb[c] - bnm[c] * sc;
      }
#pragma unroll
      for (int reg = 0; reg < 4; ++reg) {
        int r = r0 + reg;
        float v = acc[ni][reg] + bv;
        if (ACT == 1) v = fmaxf(v, 0.f);
        else if (ACT == 3) v = fmaxf(v * sc + sh, 0.f);
        acc[ni][reg] = v;  // stash post-activation value for alpha epilogue
        if (r < M) C[(size_t)r * N + c] = (OUT_T)v;
      }
    }
  }

  if (J > 0) {
#pragma unroll
    for (int j = 0; j < J; ++j) {
      float pj[4];
#pragma unroll
      for (int ni = 0; ni < 4; ++ni)
        pj[ni] = Pa[j * 128 + wn + ni * 16 + ln15];
      float s[4];
#pragma unroll
      for (int reg = 0; reg < 4; ++reg)
        s[reg] = acc[0][reg] * pj[0] + acc[1][reg] * pj[1] +
                 acc[2][reg] * pj[2] + acc[3][reg] * pj[3];
#pragma unroll
      for (int d = 1; d < 16; d <<= 1)
#pragma unroll
        for (int reg = 0; reg < 4; ++reg)
          s[reg] += __shfl_xor(s[reg], d);
      if (ln15 == 0) {
#pragma unroll
        for (int reg = 0; reg < 4; ++reg) {
          int r = bm + wm + quad * 4 + reg;
          if (r < M) atomicAdd(&asad[(size_t)r * J + j], s[reg]);
        }
      }
    }
  }
}

// ---------------- FUSED layer-2: agg (K=128, H=4) + GEMM (K=512) in one kernel ------
// Phase A: 4 waves x 8 nodes aggregate into LDS Af[32][512] (bf16, XOR-swizzled
// rows to break the 1024B-stride bank conflict). Values bit-identical to the old
// aggb round-trip (same pack2bf). Phase B: exact gemm32 body with af from LDS.

__global__ __launch_bounds__(256) void fused_l2(const bf16_t* __restrict__ f,
                                                const float* __restrict__ asadB,
                                                const int* __restrict__ cnt,
                                                const int* __restrict__ col,
                                                const bf16_t* __restrict__ Bt,
                                                const float* __restrict__ bias,
                                                const float* __restrict__ bng,
                                                const float* __restrict__ bnb,
                                                const float* __restrict__ bnm,
                                                const float* __restrict__ bnv,
                                                bf16_t* __restrict__ C,
                                                const float* __restrict__ Pa,
                                                float* __restrict__ asad,
                                                int M, int N, int K) {
  __shared__ __align__(16) bf16_t Af[32 * 512];   // 32 KB
  __shared__ __align__(16) bf16_t Bs[128 * 64];   // 16 KB
  __shared__ int sb[4][64];
  __shared__ float4 wl[4][64];

  const int t = threadIdx.x;
  const int wave = t >> 6, lane = t & 63;
  const int ln15 = lane & 15, quad = lane >> 4;
  const char* fb = (const char*)f;
  const size_t loff = (size_t)lane * 4;  // KC=2: 2 bf16 per lane

  // ---------------- Phase A: aggregate 8 nodes per wave ----------------
  for (int i = 0; i < 8; ++i) {
    const int n = blockIdx.x * 32 + wave * 8 + i;
    const int lrow = wave * 8 + i;
    const int r0 = n * CAP;
    const int deg = cnt[n];
    const int r1 = r0 + deg;
    const float4 adv = *(const float4*)&asadB[(size_t)n * 8 + 4];

    float acc[4][2];
#pragma unroll
    for (int j = 0; j < 4; ++j) { acc[j][0] = 0.f; acc[j][1] = 0.f; }

    if (deg <= 64) {
      const bool valid = lane < deg;
      int s = n;
      float e0 = -1e30f, e1 = -1e30f, e2 = -1e30f, e3 = -1e30f;
      if (valid) {
        s = col[r0 + lane];
        const float4 av = *(const float4*)&asadB[(size_t)s * 8];
        e0 = lrelu(av.x + adv.x); e1 = lrelu(av.y + adv.y);
        e2 = lrelu(av.z + adv.z); e3 = lrelu(av.w + adv.w);
      }
      float m0 = e0, m1 = e1, m2 = e2, m3 = e3;
#pragma unroll
      for (int d = 1; d < 64; d <<= 1) {
        m0 = fmaxf(m0, __shfl_xor(m0, d)); m1 = fmaxf(m1, __shfl_xor(m1, d));
        m2 = fmaxf(m2, __shfl_xor(m2, d)); m3 = fmaxf(m3, __shfl_xor(m3, d));
      }
      float x0 = valid ? __expf(e0 - m0) : 0.f;
      float x1 = valid ? __expf(e1 - m1) : 0.f;
      float x2 = valid ? __expf(e2 - m2) : 0.f;
      float x3 = valid ? __expf(e3 - m3) : 0.f;
      float d0 = x0, d1 = x1, d2 = x2, d3 = x3;
#pragma unroll
      for (int d = 1; d < 64; d <<= 1) {
        d0 += __shfl_xor(d0, d); d1 += __shfl_xor(d1, d);
        d2 += __shfl_xor(d2, d); d3 += __shfl_xor(d3, d);
      }
      sb[wave][lane] = s * 256;
      wl[wave][lane] = valid ? make_float4(x0 / (d0 + 1e-16f), x1 / (d1 + 1e-16f),
                                           x2 / (d2 + 1e-16f), x3 / (d3 + 1e-16f))
                             : make_float4(0.f, 0.f, 0.f, 0.f);
      __builtin_amdgcn_wave_barrier();

      const int nb = (deg + 7) >> 3;
      uint32_t bA[8], bB[8];
      auto loadb = [&](int g, uint32_t* b) {
#pragma unroll
        for (int k = 0; k < 8; ++k)
          b[k] = *(const uint32_t*)(fb + (size_t)sb[wave][g + k] + loff);
      };
      auto fmab = [&](int g, const uint32_t* b) {
#pragma unroll
        for (int k = 0; k < 8; ++k) {
          const float4 w = wl[wave][g + k];
          float v0 = bflo(b[k]), v1 = bfhi(b[k]);
          acc[0][0] += w.x * v0; acc[0][1] += w.x * v1;
          acc[1][0] += w.y * v0; acc[1][1] += w.y * v1;
          acc[2][0] += w.z * v0; acc[2][1] += w.z * v1;
          acc[3][0] += w.w * v0; acc[3][1] += w.w * v1;
        }
      };
      loadb(0, bA);
      int ii = 0;
      while (ii + 2 <= nb) {
        loadb((ii + 1) * 8, bB);
        fmab(ii * 8, bA);
        if (ii + 2 < nb) loadb((ii + 2) * 8, bA);
        fmab((ii + 1) * 8, bB);
        ii += 2;
      }
      if (ii < nb) fmab(ii * 8, bA);
      __builtin_amdgcn_wave_barrier();  // fence before next node overwrites sb/wl
    } else {
      float m0 = -1e30f, m1 = -1e30f, m2 = -1e30f, m3 = -1e30f;
      for (int q = r0 + lane; q < r1; q += 64) {
        const float4 av = *(const float4*)&asadB[(size_t)col[q] * 8];
        m0 = fmaxf(m0, lrelu(av.x + adv.x)); m1 = fmaxf(m1, lrelu(av.y + adv.y));
        m2 = fmaxf(m2, lrelu(av.z + adv.z)); m3 = fmaxf(m3, lrelu(av.w + adv.w));
      }
#pragma unroll
      for (int d = 1; d < 64; d <<= 1) {
        m0 = fmaxf(m0, __shfl_xor(m0, d)); m1 = fmaxf(m1, __shfl_xor(m1, d));
        m2 = fmaxf(m2, __shfl_xor(m2, d)); m3 = fmaxf(m3, __shfl_xor(m3, d));
      }
      float d0 = 0.f, d1 = 0.f, d2 = 0.f, d3 = 0.f;
      for (int q = r0 + lane; q < r1; q += 64) {
        const float4 av = *(const float4*)&asadB[(size_t)col[q] * 8];
        d0 += __expf(lrelu(av.x + adv.x) - m0); d1 += __expf(lrelu(av.y + adv.y) - m1);
        d2 += __expf(lrelu(av.z + adv.z) - m2); d3 += __expf(lrelu(av.w + adv.w) - m3);
      }
#pragma unroll
      for (int d = 1; d < 64; d <<= 1) {
        d0 += __shfl_xor(d0, d); d1 += __shfl_xor(d1, d);
        d2 += __shfl_xor(d2, d); d3 += __shfl_xor(d3, d);
      }
      const float i0 = 1.f / (d0 + 1e-16f), i1 = 1.f / (d1 + 1e-16f);
      const float i2 = 1.f / (d2 + 1e-16f), i3 = 1.f / (d3 + 1e-16f);
      for (int base = r0; base < r1; base += 64) {
        const int ne = min(64, r1 - base);
        if (lane < ne) {
          const int s = col[base + lane];
          const float4 av = *(const float4*)&asadB[(size_t)s * 8];
          sb[wave][lane] = s * 256;
          wl[wave][lane] = make_float4(__expf(lrelu(av.x + adv.x) - m0) * i0,
                                       __expf(lrelu(av.y + adv.y) - m1) * i1,
                                       __expf(lrelu(av.z + adv.z) - m2) * i2,
                                       __expf(lrelu(av.w + adv.w) - m3) * i3);
        }
        __builtin_amdgcn_wave_barrier();
        for (int g = 0; g < ne; ++g) {
          uint32_t b = *(const uint32_t*)(fb + (size_t)sb[wave][g] + loff);
          const float4 w = wl[wave][g];
          float v0 = bflo(b), v1 = bfhi(b);
          acc[0][0] += w.x * v0; acc[0][1] += w.x * v1;
          acc[1][0] += w.y * v0; acc[1][1] += w.y * v1;
          acc[2][0] += w.z * v0; acc[2][1] += w.z * v1;
          acc[3][0] += w.w * v0; acc[3][1] += w.w * v1;
        }
        __builtin_amdgcn_wave_barrier();
      }
    }

    // write node's 512-wide aggregated row into LDS (swizzled), bit-identical pack
    const unsigned xr = (unsigned)((lrow & 7) << 4);
#pragma unroll
    for (int j = 0; j < 4; ++j) {
      unsigned off = (unsigned)(lrow * 1024 + j * 256 + lane * 4) ^ xr;
      *(uint32_t*)((char*)Af + off) = pack2bf(acc[j][0], acc[j][1]);
    }
  }
  __syncthreads();

  // ---------------- Phase B: gemm32 body, A resident in LDS ----------------
  constexpr int TN = 128, BK = 64;
  constexpr int NRB = (TN * BK * 2) / 4096;  // 4
  const int bm = blockIdx.x * 32;
  const int wm = (wave >> 1) * 16;
  const int wn = (wave & 1) * 64;
  const size_t strideB = (size_t)K * 2;
  const char* gB = (const char*)Bt;

  f32x4 acc[4];
#pragma unroll
  for (int ni = 0; ni < 4; ++ni) acc[ni] = (f32x4){0.f, 0.f, 0.f, 0.f};

  for (int k0 = 0; k0 < K; k0 += BK) {
#pragma unroll
    for (int r = 0; r < NRB; ++r) {
      int base = (wave * NRB + r) * 1024;
      int flat = base + lane * 16;
      int row = flat >> 7;
      const char* gp = gB + (size_t)row * strideB + (size_t)(k0 * 2) + (flat & 127);
      __builtin_amdgcn_global_load_lds((const AS1 void*)gp,
                                       (AS3 void*)((char*)Bs + base), 16, 0, 0);
    }
    __syncthreads();
#pragma unroll
    for (int kk = 0; kk < BK; kk += 32) {
      const int arow = wm + ln15;
      unsigned abyte = (unsigned)(arow * 1024 + (k0 + kk) * 2 + quad * 16) ^
                       (unsigned)((arow & 7) << 4);
      bf16x8 af = *(const bf16x8*)((const char*)Af + abyte);
      bf16x8 bfr[4];
#pragma unroll
      for (int ni = 0; ni < 4; ++ni)
        bfr[ni] = *(const bf16x8*)&Bs[(wn + ni * 16 + ln15) * BK + kk + quad * 8];
#pragma unroll
      for (int ni = 0; ni < 4; ++ni)
        acc[ni] = __builtin_amdgcn_mfma_f32_16x16x32_bf16(af, bfr[ni], acc[ni], 0, 0, 0);
    }
    __syncthreads();
  }

  {
    int r0 = bm + wm + quad * 4;
#pragma unroll
    for (int ni = 0; ni < 4; ++ni) {
      int c = wn + ni * 16 + ln15;
      float bv = bias ? bias[c] : 0.f;
      float sc = bng[c] * rsqrtf(bnv[c] + 1e-5f);
      float sh = bnb[c] - bnm[c] * sc;
#pragma unroll
      for (int reg = 0; reg < 4; ++reg) {
        int r = r0 + reg;
        float v = acc[ni][reg] + bv;
        v = fmaxf(v * sc + sh, 0.f);
        acc[ni][reg] = v;
        if (r < M) C[(size_t)r * N + c] = (bf16_t)v;
      }
    }
  }

  {
    constexpr int J = 2;
#pragma unroll
    for (int j = 0; j < J; ++j) {
      float pj[4];
#pragma unroll
      for (int ni = 0; ni < 4; ++ni)
        pj[ni] = Pa[j * 128 + wn + ni * 16 + ln15];
      float s[4];
#pragma unroll
      for (int reg = 0; reg < 4; ++reg)
        s[reg] = acc[0][reg] * pj[0] + acc[1][reg] * pj[1] +
                 acc[2][reg] * pj[2] + acc[3][reg] * pj[3];
#pragma unroll
      for (int d = 1; d < 16; d <<= 1)
#pragma unroll
        for (int reg = 0; reg < 4; ++reg)
          s[reg] += __shfl_xor(s[reg], d);
      if (ln15 == 0) {
#pragma unroll
        for (int reg = 0; reg < 4; ++reg) {
          int r = bm + wm + quad * 4 + reg;
          if (r < M) atomicAdd(&asad[(size_t)r * J + j], s[reg]);
        }
      }
    }
  }
}

// ---------------- input-space GAT aggregation, H=4: wave/node, 2 nodes/block ---------
// Edge loop: padded full 8-edge batches (invalid lanes carry weight 0 and point at
// the node's own row), two-deep ping-pong prefetch of the gathered rows.

template <int K>
__global__ __launch_bounds__(128) void gat_agg_in4(const bf16_t* __restrict__ f,
                                                   const float* __restrict__ asad,
                                                   const int* __restrict__ cnt,
                                                   const int* __restrict__ col,
                                                   bf16_t* __restrict__ agg) {
  constexpr int KC = K / 64;
  const int wv = threadIdx.x >> 6, lane = threadIdx.x & 63;
  const int n = blockIdx.x * 2 + wv;
  __shared__ int sb[2][64];
  __shared__ float4 wl[2][64];

  const int r0 = n * CAP;
  const int deg = cnt[n];
  const int r1 = r0 + deg;
  const float4 adv = *(const float4*)&asad[(size_t)n * 8 + 4];
  const char* fb = (const char*)f;
  const size_t loff = (size_t)lane * (KC * 2);

  float acc[4][KC];
#pragma unroll
  for (int j = 0; j < 4; ++j)
#pragma unroll
    for (int q = 0; q < KC; ++q) acc[j][q] = 0.f;

  auto edge_fma = [&](const char* gp, float4 w4) {
    if (KC == 4) {
      uint2 b = *(const uint2*)gp;
      float v0 = bflo(b.x), v1 = bfhi(b.x), v2 = bflo(b.y), v3 = bfhi(b.y);
      acc[0][0] += w4.x * v0; acc[0][1] += w4.x * v1; acc[0][2] += w4.x * v2; acc[0][3] += w4.x * v3;
      acc[1][0] += w4.y * v0; acc[1][1] += w4.y * v1; acc[1][2] += w4.y * v2; acc[1][3] += w4.y * v3;
      acc[2][0] += w4.z * v0; acc[2][1] += w4.z * v1; acc[2][2] += w4.z * v2; acc[2][3] += w4.z * v3;
      acc[3][0] += w4.w * v0; acc[3][1] += w4.w * v1; acc[3][2] += w4.w * v2; acc[3][3] += w4.w * v3;
    } else {
      uint32_t b = *(const uint32_t*)gp;
      float v0 = bflo(b), v1 = bfhi(b);
      acc[0][0] += w4.x * v0; acc[0][1] += w4.x * v1;
      acc[1][0] += w4.y * v0; acc[1][1] += w4.y * v1;
      acc[2][0] += w4.z * v0; acc[2][1] += w4.z * v1;
      acc[3][0] += w4.w * v0; acc[3][1] += w4.w * v1;
    }
  };

  if (deg <= 64) {
    const bool valid = lane < deg;
    int s = n;  // invalid lanes: self row (safe address), weight 0
    float e0 = -1e30f, e1 = -1e30f, e2 = -1e30f, e3 = -1e30f;
    if (valid) {
      s = col[r0 + lane];
      const float4 av = *(const float4*)&asad[(size_t)s * 8];
      e0 = lrelu(av.x + adv.x); e1 = lrelu(av.y + adv.y);
      e2 = lrelu(av.z + adv.z); e3 = lrelu(av.w + adv.w);
    }
    float m0 = e0, m1 = e1, m2 = e2, m3 = e3;
#pragma unroll
    for (int d = 1; d < 64; d <<= 1) {
      m0 = fmaxf(m0, __shfl_xor(m0, d)); m1 = fmaxf(m1, __shfl_xor(m1, d));
      m2 = fmaxf(m2, __shfl_xor(m2, d)); m3 = fmaxf(m3, __shfl_xor(m3, d));
    }
    float x0 = valid ? __expf(e0 - m0) : 0.f;
    float x1 = valid ? __expf(e1 - m1) : 0.f;
    float x2 = valid ? __expf(e2 - m2) : 0.f;
    float x3 = valid ? __expf(e3 - m3) : 0.f;
    float d0 = x0, d1 = x1, d2 = x2, d3 = x3;
#pragma unroll
    for (int d = 1; d < 64; d <<= 1) {
      d0 += __shfl_xor(d0, d); d1 += __shfl_xor(d1, d);
      d2 += __shfl_xor(d2, d); d3 += __shfl_xor(d3, d);
    }
    sb[wv][lane] = s * (K * 2);
    wl[wv][lane] = valid ? make_float4(x0 / (d0 + 1e-16f), x1 / (d1 + 1e-16f),
                                       x2 / (d2 + 1e-16f), x3 / (d3 + 1e-16f))
                         : make_float4(0.f, 0.f, 0.f, 0.f);
    __builtin_amdgcn_wave_barrier();

    const int nb = (deg + 7) >> 3;  // >=1 (self-loop guarantees deg>=1)
    uint2 bA[8], bB[8];
    auto loadb = [&](int g, uint2* b) {
#pragma unroll
      for (int k = 0; k < 8; ++k) {
        const char* gp = fb + (size_t)sb[wv][g + k] + loff;
        if (KC == 4) b[k] = *(const uint2*)gp;
        else         b[k].x = *(const uint32_t*)gp;
      }
    };
    auto fmab = [&](int g, const uint2* b) {
#pragma unroll
      for (int k = 0; k < 8; ++k) {
        const float4 w = wl[wv][g + k];
        if (KC == 4) {
          float v0 = bflo(b[k].x), v1 = bfhi(b[k].x), v2 = bflo(b[k].y), v3 = bfhi(b[k].y);
          acc[0][0] += w.x * v0; acc[0][1] += w.x * v1; acc[0][2] += w.x * v2; acc[0][3] += w.x * v3;
          acc[1][0] += w.y * v0; acc[1][1] += w.y * v1; acc[1][2] += w.y * v2; acc[1][3] += w.y * v3;
          acc[2][0] += w.z * v0; acc[2][1] += w.z * v1; acc[2][2] += w.z * v2; acc[2][3] += w.z * v3;
          acc[3][0] += w.w * v0; acc[3][1] += w.w * v1; acc[3][2] += w.w * v2; acc[3][3] += w.w * v3;
        } else {
          float v0 = bflo(b[k].x), v1 = bfhi(b[k].x);
          acc[0][0] += w.x * v0; acc[0][1] += w.x * v1;
          acc[1][0] += w.y * v0; acc[1][1] += w.y * v1;
          acc[2][0] += w.z * v0; acc[2][1] += w.z * v1;
          acc[3][0] += w.w * v0; acc[3][1] += w.w * v1;
        }
      }
    };
    loadb(0, bA);
    int i = 0;
    while (i + 2 <= nb) {
      loadb((i + 1) * 8, bB);
      fmab(i * 8, bA);
      if (i + 2 < nb) loadb((i + 2) * 8, bA);
      fmab((i + 1) * 8, bB);
      i += 2;
    }
    if (i < nb) fmab(i * 8, bA);
  } else {
    float m0 = -1e30f, m1 = -1e30f, m2 = -1e30f, m3 = -1e30f;
    for (int i = r0 + lane; i < r1; i += 64) {
      const float4 av = *(const float4*)&asad[(size_t)col[i] * 8];
      m0 = fmaxf(m0, lrelu(av.x + adv.x)); m1 = fmaxf(m1, lrelu(av.y + adv.y));
      m2 = fmaxf(m2, lrelu(av.z + adv.z)); m3 = fmaxf(m3, lrelu(av.w + adv.w));
    }
#pragma unroll
    for (int d = 1; d < 64; d <<= 1) {
      m0 = fmaxf(m0, __shfl_xor(m0, d)); m1 = fmaxf(m1, __shfl_xor(m1, d));
      m2 = fmaxf(m2, __shfl_xor(m2, d)); m3 = fmaxf(m3, __shfl_xor(m3, d));
    }
    float d0 = 0.f, d1 = 0.f, d2 = 0.f, d3 = 0.f;
    for (int i = r0 + lane; i < r1; i += 64) {
      const float4 av = *(const float4*)&asad[(size_t)col[i] * 8];
      d0 += __expf(lrelu(av.x + adv.x) - m0); d1 += __expf(lrelu(av.y + adv.y) - m1);
      d2 += __expf(lrelu(av.z + adv.z) - m2); d3 += __expf(lrelu(av.w + adv.w) - m3);
    }
#pragma unroll
    for (int d = 1; d < 64; d <<= 1) {
      d0 += __shfl_xor(d0, d); d1 += __shfl_xor(d1, d);
      d2 += __shfl_xor(d2, d); d3 += __shfl_xor(d3, d);
    }
    const float i0 = 1.f / (d0 + 1e-16f), i1 = 1.f / (d1 + 1e-16f);
    const float i2 = 1.f / (d2 + 1e-16f), i3 = 1.f / (d3 + 1e-16f);
    for (int base = r0; base < r1; base += 64) {
      const int ne = min(64, r1 - base);
      if (lane < ne) {
        const int s = col[base + lane];
        const float4 av = *(const float4*)&asad[(size_t)s * 8];
        sb[wv][lane] = s * (K * 2);
        wl[wv][lane] = make_float4(__expf(lrelu(av.x + adv.x) - m0) * i0,
                                   __expf(lrelu(av.y + adv.y) - m1) * i1,
                                   __expf(lrelu(av.z + adv.z) - m2) * i2,
                                   __expf(lrelu(av.w + adv.w) - m3) * i3);
      }
      __builtin_amdgcn_wave_barrier();
      for (int g = 0; g < ne; ++g)
        edge_fma(fb + (size_t)sb[wv][g] + loff, wl[wv][g]);
      __builtin_amdgcn_wave_barrier();
    }
  }

#pragma unroll
  for (int j = 0; j < 4; ++j) {
    if (KC == 4) {
      uint2 ov;
      ov.x = pack2bf(acc[j][0], acc[j][1]);
      ov.y = pack2bf(acc[j][2], acc[j][3]);
      *(uint2*)&agg[(size_t)n * (4 * K) + j * K + lane * 4] = ov;
    } else {
      *(uint32_t*)&agg[(size_t)n * (4 * K) + j * K + lane * 2] = pack2bf(acc[j][0], acc[j][1]);
    }
  }
}

// ---------------- input-space GAT aggregation, H=1 (K=128): 2 nodes/block ------------

__global__ __launch_bounds__(128) void gat_agg_in1(const bf16_t* __restrict__ f,
                                                   const float* __restrict__ asad,
                                                   const int* __restrict__ cnt,
                                                   const int* __restrict__ col,
                                                   bf16_t* __restrict__ agg) {
  const int wv = threadIdx.x >> 6, lane = threadIdx.x & 63;
  const int n = blockIdx.x * 2 + wv;
  __shared__ int sb[2][64];
  __shared__ float wl[2][64];

  const int r0 = n * CAP;
  const int deg = cnt[n];
  const int r1 = r0 + deg;
  const float adv = asad[(size_t)n * 2 + 1];
  const char* fb = (const char*)f;
  const size_t loff = (size_t)lane * 4;
  float a0 = 0.f, a1 = 0.f;

  auto fma2 = [&](uint32_t v, float w) { a0 += w * bflo(v); a1 += w * bfhi(v); };

  if (deg <= 64) {
    const bool valid = lane < deg;
    int s = n;  // invalid lanes: self row, weight 0
    float e = -1e30f;
    if (valid) { s = col[r0 + lane]; e = lrelu(asad[(size_t)s * 2] + adv); }
    float m = e;
#pragma unroll
    for (int d = 1; d < 64; d <<= 1) m = fmaxf(m, __shfl_xor(m, d));
    float x = valid ? __expf(e - m) : 0.f;
    float den = x;
#pragma unroll
    for (int d = 1; d < 64; d <<= 1) den += __shfl_xor(den, d);
    sb[wv][lane] = s * 256;
    wl[wv][lane] = valid ? x / (den + 1e-16f) : 0.f;
    __builtin_amdgcn_wave_barrier();

    const int nb = (deg + 7) >> 3;
    uint32_t bA[8], bB[8];
    auto loadb = [&](int g, uint32_t* b) {
#pragma unroll
      for (int k = 0; k < 8; ++k)
        b[k] = *(const uint32_t*)(fb + (size_t)sb[wv][g + k] + loff);
    };
    auto fmab = [&](int g, const uint32_t* b) {
#pragma unroll
      for (int k = 0; k < 8; ++k) {
        const float w = wl[wv][g + k];
        a0 += w * bflo(b[k]); a1 += w * bfhi(b[k]);
      }
    };
    loadb(0, bA);
    int i = 0;
    while (i + 2 <= nb) {
      loadb((i + 1) * 8, bB);
      fmab(i * 8, bA);
      if (i + 2 < nb) loadb((i + 2) * 8, bA);
      fmab((i + 1) * 8, bB);
      i += 2;
    }
    if (i < nb) fmab(i * 8, bA);
  } else {
    float m = -1e30f;
    for (int i = r0 + lane; i < r1; i += 64) m = fmaxf(m, lrelu(asad[(size_t)col[i] * 2] + adv));
#pragma unroll
    for (int d = 1; d < 64; d <<= 1) m = fmaxf(m, __shfl_xor(m, d));
    float den = 0.f;
    for (int i = r0 + lane; i < r1; i += 64) den += __expf(lrelu(asad[(size_t)col[i] * 2] + adv) - m);
#pragma unroll
    for (int d = 1; d < 64; d <<= 1) den += __shfl_xor(den, d);
    const float dinv = 1.f / (den + 1e-16f);
    for (int base = r0; base < r1; base += 64) {
      const int ne = min(64, r1 - base);
      if (lane < ne) {
        const int s = col[base + lane];
        sb[wv][lane] = s * 256;
        wl[wv][lane] = __expf(lrelu(asad[(size_t)s * 2] + adv) - m) * dinv;
      }
      __builtin_amdgcn_wave_barrier();
      for (int g = 0; g < ne; ++g)
        fma2(*(const uint32_t*)(fb + (size_t)sb[wv][g] + loff), wl[wv][g]);
      __builtin_amdgcn_wave_barrier();
    }
  }
  *(uint32_t*)&agg[(size_t)n * 128 + lane * 2] = pack2bf(a0, a1);
}

// ---------------- fused classifier tail (FROZEN: exact known-pass bytes) ----------------
// Empirically threshold-sensitive to restructuring (R7/R8 failures) -> do not modify.

__global__ __launch_bounds__(256) void mlp_tail(const bf16_t* __restrict__ A,
                                                const bf16_t* __restrict__ M3t,
                                                const float* __restrict__ bm,
                                                const bf16_t* __restrict__ l2t,
                                                const float* __restrict__ l2b,
                                                const bf16_t* __restrict__ l3t,
                                                const float* __restrict__ l3b,
                                                float* __restrict__ out, int M) {
  __shared__ __align__(16) bf16_t As[128 * 128];
  __shared__ __align__(16) bf16_t Ws[128 * 128];
  const int t = threadIdx.x, wave = t >> 6, lane = t & 63;
  const int ln15 = lane & 15, quad = lane >> 4;
  const int bmr = blockIdx.x * 128;
  const int rowLim = M - 1 - bmr;

#pragma unroll
  for (int r = 0; r < 8; ++r) {
    int base = (wave * 8 + r) * 1024;
    int flat = base + lane * 16;
    int row = flat >> 8;
    int grow = row < rowLim ? row : rowLim;
    const char* gp = (const char*)A + (size_t)grow * 256 + (flat & 255);
    __builtin_amdgcn_global_load_lds((const AS1 void*)gp,
                                     (AS3 void*)((char*)As + base), 16, 0, 0);
  }
#pragma unroll
  for (int r = 0; r < 8; ++r) {
    int base = (wave * 8 + r) * 1024;
    __builtin_amdgcn_global_load_lds((const AS1 void*)((const char*)M3t + base + lane * 16),
                                     (AS3 void*)((char*)Ws + base), 16, 0, 0);
  }
  __syncthreads();

  const int wm = wave * 32;
  f32x4 a1[2][8];
#pragma unroll
  for (int mi = 0; mi < 2; ++mi)
#pragma unroll
    for (int ni = 0; ni < 8; ++ni) a1[mi][ni] = (f32x4){0.f, 0.f, 0.f, 0.f};
#pragma unroll
  for (int kk = 0; kk < 128; kk += 32) {
    bf16x8 af[2];
#pragma unroll
    for (int mi = 0; mi < 2; ++mi)
      af[mi] = *(const bf16x8*)&As[(wm + mi * 16 + ln15) * 128 + kk + quad * 8];
#pragma unroll
    for (int ni = 0; ni < 8; ++ni) {
      bf16x8 bf = *(const bf16x8*)&Ws[(ni * 16 + ln15) * 128 + kk + quad * 8];
#pragma unroll
      for (int mi = 0; mi < 2; ++mi)
        a1[mi][ni] = __builtin_amdgcn_mfma_f32_16x16x32_bf16(af[mi], bf, a1[mi][ni], 0, 0, 0);
    }
  }
  __syncthreads();

#pragma unroll
  for (int r = 0; r < 4; ++r) {
    int base = (wave * 4 + r) * 1024;
    __builtin_amdgcn_global_load_lds((const AS1 void*)((const char*)l2t + base + lane * 16),
                                     (AS3 void*)((char*)Ws + base), 16, 0, 0);
  }
#pragma unroll
  for (int r = 0; r < 2; ++r) {
    int base = (wave * 2 + r) * 1024;
    __builtin_amdgcn_global_load_lds((const AS1 void*)((const char*)l3t + base + lane * 16),
                                     (AS3 void*)((char*)Ws + 8192 * 2 + base), 16, 0, 0);
  }
#pragma unroll
  for (int mi = 0; mi < 2; ++mi) {
    int r0 = wm + mi * 16 + quad * 4;
#pragma unroll
    for (int ni = 0; ni < 8; ++ni) {
      int c = ni * 16 + ln15;
      float bv = bm[c];
#pragma unroll
      for (int reg = 0; reg < 4; ++reg)
        As[(r0 + reg) * 128 + c] = (bf16_t)fmaxf(a1[mi][ni][reg] + bv, 0.f);
    }
  }
  __syncthreads();

  f32x4 a2[2][4];
#pragma unroll
  for (int mi = 0; mi < 2; ++mi)
#pragma unroll
    for (int ni = 0; ni < 4; ++ni) a2[mi][ni] = (f32x4){0.f, 0.f, 0.f, 0.f};
#pragma unroll
  for (int kk = 0; kk < 128; kk += 32) {
    bf16x8 af[2];
#pragma unroll
    for (int mi = 0; mi < 2; ++mi)
      af[mi] = *(const bf16x8*)&As[(wm + mi * 16 + ln15) * 128 + kk + quad * 8];
#pragma unroll
    for (int ni = 0; ni < 4; ++ni) {
      bf16x8 bf = *(const bf16x8*)&Ws[(ni * 16 + ln15) * 128 + kk + quad * 8];
#pragma unroll
      for (int mi = 0; mi < 2; ++mi)
        a2[mi][ni] = __builtin_amdgcn_mfma_f32_16x16x32_bf16(af[mi], bf, a2[mi][ni], 0, 0, 0);
    }
  }
  __syncthreads();

#pragma unroll
  for (int mi = 0; mi < 2; ++mi) {
    int r0 = wm + mi * 16 + quad * 4;
#pragma unroll
    for (int ni = 0; ni < 4; ++ni) {
      int c = ni * 16 + ln15;
      float bv = l2b[c];
#pragma unroll
      for (int reg = 0; reg < 4; ++reg)
        As[(r0 + reg) * 64 + c] = (bf16_t)fmaxf(a2[mi][ni][reg] + bv, 0.f);
    }
  }
  __syncthreads();

  f32x4 a3[2][4];
#pragma unroll
  for (int mi = 0; mi < 2; ++mi)
#pragma unroll
    for (int ni = 0; ni < 4; ++ni) a3[mi][ni] = (f32x4){0.f, 0.f, 0.f, 0.f};
#pragma unroll
  for (int kk = 0; kk < 64; kk += 32) {
    bf16x8 af[2];
#pragma unroll
    for (int mi = 0; mi < 2; ++mi)
      af[mi] = *(const bf16x8*)&As[(wm + mi * 16 + ln15) * 64 + kk + quad * 8];
#pragma unroll
    for (int ni = 0; ni < 4; ++ni) {
      bf16x8 bf = *(const bf16x8*)&Ws[8192 + (ni * 16 + ln15) * 64 + kk + quad * 8];
#pragma unroll
      for (int mi = 0; mi < 2; ++mi)
        a3[mi][ni] = __builtin_amdgcn_mfma_f32_16x16x32_bf16(af[mi], bf, a3[mi][ni], 0, 0, 0);
    }
  }
#pragma unroll
  for (int mi = 0; mi < 2; ++mi) {
    int r0 = wm + mi * 16 + quad * 4;
#pragma unroll
    for (int ni = 0; ni < 4; ++ni) {
      int c = ni * 16 + ln15;
      float bv = l3b[c];
#pragma unroll
      for (int reg = 0; reg < 4; ++reg) {
        int r = bmr + r0 + reg;
        if (r < M) {
          float v = a3[mi][ni][reg] + bv;
          out[(size_t)r * 64 + c] = 1.f / (1.f + __expf(-v));
        }
      }
    }
  }
}

// ---------------- launch ----------------

extern "C" void kernel_launch(void* const* d_in, const int* in_sizes, int n_in,
                              void* d_out, int out_size, void* d_ws, size_t ws_size,
                              hipStream_t stream) {
  const float* x      = (const float*)d_in[0];
  const int*   ei     = (const int*)d_in[1];
  const float* W1     = (const float*)d_in[2];
  const float* a_src1 = (const float*)d_in[3];
  const float* a_dst1 = (const float*)d_in[4];
  const float* b1     = (const float*)d_in[5];
  const float* W2     = (const float*)d_in[6];
  const float* a_src2 = (const float*)d_in[7];
  const float* a_dst2 = (const float*)d_in[8];
  const float* b2     = (const float*)d_in[9];
  const float* W3     = (const float*)d_in[10];
  const float* a_src3 = (const float*)d_in[11];
  const float* a_dst3 = (const float*)d_in[12];
  const float* b3     = (const float*)d_in[13];
  const float* bn1g = (const float*)d_in[14];
  const float* bn1b = (const float*)d_in[15];
  const float* bn1m = (const float*)d_in[16];
  const float* bn1v = (const float*)d_in[17];
  const float* bn2g = (const float*)d_in[18];
  const float* bn2b = (const float*)d_in[19];
  const float* bn2m = (const float*)d_in[20];
  const float* bn2v = (const float*)d_in[21];
  const float* l1w = (const float*)d_in[22];
  const float* l1b = (const float*)d_in[23];
  const float* l2w = (const float*)d_in[24];
  const float* l2b = (const float*)d_in[25];
  const float* l3w = (const float*)d_in[26];
  const float* l3b = (const float*)d_in[27];
  float* out = (float*)d_out;

  const int N = NN;
  const int E = in_sizes[1] / 2;
  const int ET = E + N;
  const int EB = (ET + 255) / 256;

  char* p = (char*)d_ws;
  auto carve = [&](size_t bytes) {
    char* q = p;
    p += (bytes + 255) & ~(size_t)255;
    return q;
  };
  bf16_t* xb    = (bf16_t*)carve((size_t)N * 256 * 2);
  bf16_t* aggb  = (bf16_t*)carve((size_t)N * 1024 * 2);
  bf16_t* f1b   = (bf16_t*)carve((size_t)N * 128 * 2);
  bf16_t* f2b   = (bf16_t*)carve((size_t)N * 128 * 2);
  float* asadA  = (float*)carve((size_t)N * 8 * 4);
  // zero-group: cnt + asadB + asadC cleared by ONE memset
  int* cnt      = (int*)carve((size_t)N * 4);
  float* asadB  = (float*)carve((size_t)N * 8 * 4);
  float* asadC  = (float*)carve((size_t)N * 2 * 4);
  const size_t zbytes = (size_t)(p - (char*)cnt);
  int* col      = (int*)carve((size_t)N * CAP * 4);
  bf16_t* Ws1t  = (bf16_t*)carve((size_t)128 * 1024 * 2);
  bf16_t* Ws2t  = (bf16_t*)carve((size_t)128 * 512 * 2);
  bf16_t* M3t   = (bf16_t*)carve((size_t)128 * 128 * 2);
  bf16_t* l2t   = (bf16_t*)carve((size_t)64 * 128 * 2);
  bf16_t* l3t   = (bf16_t*)carve((size_t)64 * 64 * 2);
  float* P1     = (float*)carve((size_t)8 * 256 * 4);
  float* P2     = (float*)carve((size_t)8 * 128 * 4);
  float* P3     = (float*)carve((size_t)2 * 128 * 4);
  float* bm     = (float*)carve((size_t)128 * 4);
  (void)ws_size; (void)n_in; (void)out_size;

  hipMemsetAsync(cnt, 0, zbytes, stream);

  Prep1Args pa;
  pa.wp.d[0] = {W1,  Ws1t, 256, 128, 4, 0.25f, 0};
  pa.wp.d[1] = {W2,  Ws2t, 128, 128, 4, 0.25f, 128};
  pa.wp.d[2] = {l2w, l2t,  128, 64,  1, 1.0f,  192};
  pa.wp.d[3] = {l3w, l3t,  64,  64,  1, 1.0f,  200};
  pa.W1 = W1; pa.as1 = a_src1; pa.ad1 = a_dst1;
  pa.W2 = W2; pa.as2 = a_src2; pa.ad2 = a_dst2;
  pa.W3 = W3; pa.as3 = a_src3; pa.ad3 = a_dst3;
  pa.P1 = P1; pa.P2 = P2; pa.P3 = P3;
  pa.W3m = W3; pa.L1w = l1w; pa.b3v = b3; pa.l1b = l1b;
  pa.M3t = M3t; pa.bm = bm;
  pa.ei = ei; pa.E = E; pa.N = N; pa.EB = EB;
  pa.cnt = cnt; pa.col = col;
  prep1<<<780 + EB, 256, 0, stream>>>(pa);

  // separate launch: consumes P1 produced by prep1 (kernel boundary = ordering)
  cast_alpha<<<N / 4, 256, 0, stream>>>(x, P1, xb, asadA);

  const int gm32 = (N + 31) / 32;   // 625 row-tiles (TM=32 GEMM and fused_l2)
  const int gm   = (N + 127) / 128; // 157 row-tiles for mlp_tail
  const int gb   = N / 2;           // 10000 gather blocks (2 nodes each)

  // --- GAT layer 1 (GEMM epilogue also emits layer-2 alpha logits) ---
  gat_agg_in4<256><<<gb, 128, 0, stream>>>(xb, asadA, cnt, col, aggb);
  gemm_mfma<3, 8, bf16_t><<<dim3(gm32, 1), 256, 0, stream>>>(
      aggb, Ws1t, b1, bn1g, bn1b, bn1m, bn1v, f1b, P2, asadB, N, 128, 1024);

  // --- GAT layer 2: fused agg+GEMM (epilogue emits layer-3 alpha logits) ---
  fused_l2<<<gm32, 256, 0, stream>>>(f1b, asadB, cnt, col, Ws2t, b2,
                                     bn2g, bn2b, bn2m, bn2v, f2b, P3, asadC,
                                     N, 128, 512);

  // --- GAT layer 3 (H=1) + fused classifier tail ---
  gat_agg_in1<<<gb, 128, 0, stream>>>(f2b, asadC, cnt, col, aggb);
  mlp_tail<<<gm, 256, 0, stream>>>(aggb, M3t, bm, l2t, l2b, l3t, l3b, out, N);
}

// Round 12
// 282.470 us; speedup vs baseline: 1.1002x; 1.1002x over previous
//
#include <hip/hip_runtime.h>
#include <cstdint>
#include <cstddef>

#define NN 20000
#define CAP 96

typedef __bf16 bf16_t;
typedef __bf16 bf16x8 __attribute__((ext_vector_type(8)));
typedef float f32x4 __attribute__((ext_vector_type(4)));

#define AS1 __attribute__((address_space(1)))
#define AS3 __attribute__((address_space(3)))

__device__ __forceinline__ float lrelu(float x) { return x >= 0.f ? x : 0.2f * x; }
__device__ __forceinline__ float bflo(uint32_t u) { return __uint_as_float(u << 16); }
__device__ __forceinline__ float bfhi(uint32_t u) { return __uint_as_float(u & 0xffff0000u); }

__device__ __forceinline__ uint32_t pack2bf(float a, float b) {
  bf16_t x = (bf16_t)a, y = (bf16_t)b;
  uint16_t ux = __builtin_bit_cast(uint16_t, x);
  uint16_t uy = __builtin_bit_cast(uint16_t, y);
  return (uint32_t)ux | ((uint32_t)uy << 16);
}

// ---------------- prep mega-kernel ----------------
// block ranges: [0,204) wprep | [204,716) alpha_proj | [716,780) merge_w3l1
//             | [780,780+EB) scatter
// NOTE: no block in this launch may READ an output produced by another block
// of this same launch (no intra-launch ordering). P1 consumers live in
// cast_alpha, a separate kernel.

struct WDesc { const float* W; bf16_t* Bt; int K; int Cw; int H; float scale; int b0; };
struct WPack { WDesc d[4]; };

struct Prep1Args {
  WPack wp;
  const float *W1, *as1, *ad1, *W2, *as2, *ad2, *W3, *as3, *ad3;
  float *P1, *P2, *P3;
  const float *W3m, *L1w, *b3v, *l1b;
  bf16_t* M3t; float* bm;
  const int* ei; int E, N, EB;
  int* cnt; int* col;
};

__global__ __launch_bounds__(256) void prep1(Prep1Args a) {
  __shared__ float tile[32][33];
  const int b = blockIdx.x;
  const int t = threadIdx.x;

  if (b < 204) {
    int i = 3;
#pragma unroll
    for (int k = 2; k >= 0; --k)
      if (b < a.wp.d[k + 1].b0) i = k;
    const WDesc de = a.wp.d[i];
    const int bi = b - de.b0;
    const int ktiles = de.K / 32;
    const int kt = bi % ktiles, rt = bi / ktiles;
    const int gc = rt * 32;
    const int h = gc / de.Cw, c0 = gc % de.Cw;
    const int tx = t & 31, ty = t >> 5;
#pragma unroll
    for (int r = 0; r < 32; r += 8)
      tile[ty + r][tx] = de.W[(size_t)(kt * 32 + ty + r) * (de.H * de.Cw) + h * de.Cw + c0 + tx];
    __syncthreads();
#pragma unroll
    for (int r = 0; r < 32; r += 8)
      de.Bt[(size_t)(c0 + ty + r) * (de.H * de.K) + h * de.K + kt * 32 + tx] =
          (bf16_t)(de.scale * tile[tx][ty + r]);
  } else if (b < 716) {
    const int kk = b - 204;
    const float *W, *asrc, *adst;
    float* P;
    int K, H, k;
    if (kk < 256)      { W = a.W1; asrc = a.as1; adst = a.ad1; P = a.P1; K = 256; H = 4; k = kk; }
    else if (kk < 384) { W = a.W2; asrc = a.as2; adst = a.ad2; P = a.P2; K = 128; H = 4; k = kk - 256; }
    else               { W = a.W3; asrc = a.as3; adst = a.ad3; P = a.P3; K = 128; H = 1; k = kk - 384; }
    for (int j = 0; j < 2 * H; ++j) {
      const int h = (j < H) ? j : j - H;
      const float* av = (j < H) ? asrc : adst;
      float pv = 0.f;
      if (t < 128) pv = W[(size_t)k * (H * 128) + h * 128 + t] * av[h * 128 + t];
#pragma unroll
      for (int d = 1; d < 64; d <<= 1) pv += __shfl_xor(pv, d);
      if (t == 0 || t == 64) tile[0][t >> 6] = pv;
      __syncthreads();
      if (t == 0) P[j * K + k] = tile[0][0] + tile[0][1];
      __syncthreads();
    }
  } else if (b < 780) {
    const int idx = (b - 716) * 256 + t;
    const int k = idx >> 7, c = idx & 127;
    float s = 0.f;
    for (int m = 0; m < 128; ++m) s += a.W3m[k * 128 + m] * a.L1w[m * 128 + c];
    a.M3t[c * 128 + k] = (bf16_t)s;
    if (k == 0) {
      float tt = a.l1b[c];
      for (int m = 0; m < 128; ++m) tt += a.b3v[m] * a.L1w[m * 128 + c];
      a.bm[c] = tt;
    }
  } else {
    // direct bucket scatter: replaces hist + scan + cursor-scatter
    const int i = (b - 780) * 256 + t;
    if (i < a.E + a.N) {
      int src, dst;
      if (i < a.E) { src = a.ei[i]; dst = a.ei[a.E + i]; }
      else         { src = i - a.E; dst = src; }
      int slot = atomicAdd(&a.cnt[dst], 1);
      a.col[(size_t)dst * CAP + slot] = src;
    }
  }
}

// ---------------- fused cast + layer-1 alpha (separate launch: consumes P1) ----------

__global__ __launch_bounds__(256) void cast_alpha(const float* __restrict__ x,
                                                  const float* __restrict__ P1,
                                                  bf16_t* __restrict__ xb,
                                                  float* __restrict__ asadA) {
  const int b = blockIdx.x, t = threadIdx.x;
  const int wv = t >> 6, lane = t & 63;
  const int n = b * 4 + wv;
  const float4 v = *(const float4*)&x[(size_t)n * 256 + lane * 4];
  uint2 ov;
  ov.x = pack2bf(v.x, v.y);
  ov.y = pack2bf(v.z, v.w);
  *(uint2*)&xb[(size_t)n * 256 + lane * 4] = ov;
  float s[8];
#pragma unroll
  for (int j = 0; j < 8; ++j) {
    const float4 pj = *(const float4*)&P1[j * 256 + lane * 4];
    s[j] = v.x * pj.x + v.y * pj.y + v.z * pj.z + v.w * pj.w;
  }
#pragma unroll
  for (int j = 0; j < 8; ++j)
#pragma unroll
    for (int d = 1; d < 64; d <<= 1) s[j] += __shfl_xor(s[j], d);
  if (lane == 0) {
#pragma unroll
    for (int j = 0; j < 8; ++j) asadA[(size_t)n * 8 + j] = s[j];
  }
}

// ---------------- bf16 MFMA GEMM: C = act(A @ Bt^T + bias) ----------------
// TM=32 x TN=128: 625 blocks (~2.4/CU). A panel read once.
// LDS XOR-swizzle (T2): 128B rows are a 16-way bank conflict on ds_read_b128;
// pre-swizzle the GLOBAL source column during global_load_lds (linear dest)
// and XOR the read address identically (rule #21 both-sides involution).
// Pure layout change: every MFMA consumes the same logical values.
// ACT: 1=relu, 3=BN(eval)+relu
// J>0: fused alpha-logit epilogue: asad[r][j] += sum_c act(C[r][c]) * Pa[j*128+c]

template <int ACT, int J, typename OUT_T>
__global__ __launch_bounds__(256) void gemm_mfma(const bf16_t* __restrict__ A,
                                                 const bf16_t* __restrict__ Bt,
                                                 const float* __restrict__ bias,
                                                 const float* __restrict__ bng,
                                                 const float* __restrict__ bnb,
                                                 const float* __restrict__ bnm,
                                                 const float* __restrict__ bnv,
                                                 OUT_T* __restrict__ C,
                                                 const float* __restrict__ Pa,
                                                 float* __restrict__ asad,
                                                 int M, int N, int K) {
  constexpr int TM = 32, TN = 128, BK = 64;
  constexpr int NRA = (TM * BK * 2) / 4096;  // 1
  constexpr int NRB = (TN * BK * 2) / 4096;  // 4
  __shared__ __align__(16) bf16_t As[TM * BK];
  __shared__ __align__(16) bf16_t Bs[TN * BK];

  const int t = threadIdx.x;
  const int wave = t >> 6, lane = t & 63;
  const int ln15 = lane & 15, quad = lane >> 4;
  const int bm = blockIdx.x * TM;
  const int wm = (wave >> 1) * 16;   // 2 wave-rows x 16 rows
  const int wn = (wave & 1) * 64;    // 2 wave-cols x 64 cols
  const int rowLimA = M - 1 - bm;
  const size_t strideAB = (size_t)K * 2;

  f32x4 acc[4];
#pragma unroll
  for (int ni = 0; ni < 4; ++ni) acc[ni] = (f32x4){0.f, 0.f, 0.f, 0.f};

  const char* gA = (const char*)(A + (size_t)bm * K);
  const char* gB = (const char*)Bt;

  for (int k0 = 0; k0 < K; k0 += BK) {
#pragma unroll
    for (int r = 0; r < NRA; ++r) {
      int base = (wave * NRA + r) * 1024;
      int flat = base + lane * 16;
      int row = flat >> 7;
      int grow = row < rowLimA ? row : rowLimA;
      int colS = (flat & 127) ^ ((row & 7) << 4);  // pre-swizzled source column
      const char* gp = gA + (size_t)grow * strideAB + (size_t)(k0 * 2) + colS;
      __builtin_amdgcn_global_load_lds((const AS1 void*)gp,
                                       (AS3 void*)((char*)As + base), 16, 0, 0);
    }
#pragma unroll
    for (int r = 0; r < NRB; ++r) {
      int base = (wave * NRB + r) * 1024;
      int flat = base + lane * 16;
      int row = flat >> 7;
      int colS = (flat & 127) ^ ((row & 7) << 4);  // pre-swizzled source column
      const char* gp = gB + (size_t)row * strideAB + (size_t)(k0 * 2) + colS;
      __builtin_amdgcn_global_load_lds((const AS1 void*)gp,
                                       (AS3 void*)((char*)Bs + base), 16, 0, 0);
    }
    __syncthreads();
#pragma unroll
    for (int kk = 0; kk < BK; kk += 32) {
      bf16x8 af, bfr[4];
      {
        const int arow = wm + ln15;
        unsigned abyte = (unsigned)(arow * 128 + (kk + quad * 8) * 2) ^
                         (unsigned)((arow & 7) << 4);
        af = *(const bf16x8*)((const char*)As + abyte);
      }
#pragma unroll
      for (int ni = 0; ni < 4; ++ni) {
        const int brow = wn + ni * 16 + ln15;
        unsigned bbyte = (unsigned)(brow * 128 + (kk + quad * 8) * 2) ^
                         (unsigned)((brow & 7) << 4);
        bfr[ni] = *(const bf16x8*)((const char*)Bs + bbyte);
      }
#pragma unroll
      for (int ni = 0; ni < 4; ++ni)
        acc[ni] = __builtin_amdgcn_mfma_f32_16x16x32_bf16(af, bfr[ni], acc[ni], 0, 0, 0);
    }
    __syncthreads();
  }

  {
    int r0 = bm + wm + quad * 4;
#pragma unroll
    for (int ni = 0; ni < 4; ++ni) {
      int c = wn + ni * 16 + ln15;
      float bv = bias ? bias[c] : 0.f;
      float sc = 1.f, sh = 0.f;
      if (ACT == 3) {
        sc = bng[c] * rsqrtf(bnv[c] + 1e-5f);
        sh = bnb[c] - bnm[c] * sc;
      }
#pragma unroll
      for (int reg = 0; reg < 4; ++reg) {
        int r = r0 + reg;
        float v = acc[ni][reg] + bv;
        if (ACT == 1) v = fmaxf(v, 0.f);
        else if (ACT == 3) v = fmaxf(v * sc + sh, 0.f);
        acc[ni][reg] = v;  // stash post-activation value for alpha epilogue
        if (r < M) C[(size_t)r * N + c] = (OUT_T)v;
      }
    }
  }

  if (J > 0) {
#pragma unroll
    for (int j = 0; j < J; ++j) {
      float pj[4];
#pragma unroll
      for (int ni = 0; ni < 4; ++ni)
        pj[ni] = Pa[j * 128 + wn + ni * 16 + ln15];
      float s[4];
#pragma unroll
      for (int reg = 0; reg < 4; ++reg)
        s[reg] = acc[0][reg] * pj[0] + acc[1][reg] * pj[1] +
                 acc[2][reg] * pj[2] + acc[3][reg] * pj[3];
#pragma unroll
      for (int d = 1; d < 16; d <<= 1)
#pragma unroll
        for (int reg = 0; reg < 4; ++reg)
          s[reg] += __shfl_xor(s[reg], d);
      if (ln15 == 0) {
#pragma unroll
        for (int reg = 0; reg < 4; ++reg) {
          int r = bm + wm + quad * 4 + reg;
          if (r < M) atomicAdd(&asad[(size_t)r * J + j], s[reg]);
        }
      }
    }
  }
}

// ---------------- input-space GAT aggregation, H=4: wave/node, 2 nodes/block ---------
// Edge loop: padded full 8-edge batches (invalid lanes carry weight 0 and point at
// the node's own row), two-deep ping-pong prefetch of the gathered rows.

template <int K>
__global__ __launch_bounds__(128) void gat_agg_in4(const bf16_t* __restrict__ f,
                                                   const float* __restrict__ asad,
                                                   const int* __restrict__ cnt,
                                                   const int* __restrict__ col,
                                                   bf16_t* __restrict__ agg) {
  constexpr int KC = K / 64;
  const int wv = threadIdx.x >> 6, lane = threadIdx.x & 63;
  const int n = blockIdx.x * 2 + wv;
  __shared__ int sb[2][64];
  __shared__ float4 wl[2][64];

  const int r0 = n * CAP;
  const int deg = cnt[n];
  const int r1 = r0 + deg;
  const float4 adv = *(const float4*)&asad[(size_t)n * 8 + 4];
  const char* fb = (const char*)f;
  const size_t loff = (size_t)lane * (KC * 2);

  float acc[4][KC];
#pragma unroll
  for (int j = 0; j < 4; ++j)
#pragma unroll
    for (int q = 0; q < KC; ++q) acc[j][q] = 0.f;

  auto edge_fma = [&](const char* gp, float4 w4) {
    if (KC == 4) {
      uint2 b = *(const uint2*)gp;
      float v0 = bflo(b.x), v1 = bfhi(b.x), v2 = bflo(b.y), v3 = bfhi(b.y);
      acc[0][0] += w4.x * v0; acc[0][1] += w4.x * v1; acc[0][2] += w4.x * v2; acc[0][3] += w4.x * v3;
      acc[1][0] += w4.y * v0; acc[1][1] += w4.y * v1; acc[1][2] += w4.y * v2; acc[1][3] += w4.y * v3;
      acc[2][0] += w4.z * v0; acc[2][1] += w4.z * v1; acc[2][2] += w4.z * v2; acc[2][3] += w4.z * v3;
      acc[3][0] += w4.w * v0; acc[3][1] += w4.w * v1; acc[3][2] += w4.w * v2; acc[3][3] += w4.w * v3;
    } else {
      uint32_t b = *(const uint32_t*)gp;
      float v0 = bflo(b), v1 = bfhi(b);
      acc[0][0] += w4.x * v0; acc[0][1] += w4.x * v1;
      acc[1][0] += w4.y * v0; acc[1][1] += w4.y * v1;
      acc[2][0] += w4.z * v0; acc[2][1] += w4.z * v1;
      acc[3][0] += w4.w * v0; acc[3][1] += w4.w * v1;
    }
  };

  if (deg <= 64) {
    const bool valid = lane < deg;
    int s = n;  // invalid lanes: self row (safe address), weight 0
    float e0 = -1e30f, e1 = -1e30f, e2 = -1e30f, e3 = -1e30f;
    if (valid) {
      s = col[r0 + lane];
      const float4 av = *(const float4*)&asad[(size_t)s * 8];
      e0 = lrelu(av.x + adv.x); e1 = lrelu(av.y + adv.y);
      e2 = lrelu(av.z + adv.z); e3 = lrelu(av.w + adv.w);
    }
    float m0 = e0, m1 = e1, m2 = e2, m3 = e3;
#pragma unroll
    for (int d = 1; d < 64; d <<= 1) {
      m0 = fmaxf(m0, __shfl_xor(m0, d)); m1 = fmaxf(m1, __shfl_xor(m1, d));
      m2 = fmaxf(m2, __shfl_xor(m2, d)); m3 = fmaxf(m3, __shfl_xor(m3, d));
    }
    float x0 = valid ? __expf(e0 - m0) : 0.f;
    float x1 = valid ? __expf(e1 - m1) : 0.f;
    float x2 = valid ? __expf(e2 - m2) : 0.f;
    float x3 = valid ? __expf(e3 - m3) : 0.f;
    float d0 = x0, d1 = x1, d2 = x2, d3 = x3;
#pragma unroll
    for (int d = 1; d < 64; d <<= 1) {
      d0 += __shfl_xor(d0, d); d1 += __shfl_xor(d1, d);
      d2 += __shfl_xor(d2, d); d3 += __shfl_xor(d3, d);
    }
    sb[wv][lane] = s * (K * 2);
    wl[wv][lane] = valid ? make_float4(x0 / (d0 + 1e-16f), x1 / (d1 + 1e-16f),
                                       x2 / (d2 + 1e-16f), x3 / (d3 + 1e-16f))
                         : make_float4(0.f, 0.f, 0.f, 0.f);
    __builtin_amdgcn_wave_barrier();

    const int nb = (deg + 7) >> 3;  // >=1 (self-loop guarantees deg>=1)
    uint2 bA[8], bB[8];
    auto loadb = [&](int g, uint2* b) {
#pragma unroll
      for (int k = 0; k < 8; ++k) {
        const char* gp = fb + (size_t)sb[wv][g + k] + loff;
        if (KC == 4) b[k] = *(const uint2*)gp;
        else         b[k].x = *(const uint32_t*)gp;
      }
    };
    auto fmab = [&](int g, const uint2* b) {
#pragma unroll
      for (int k = 0; k < 8; ++k) {
        const float4 w = wl[wv][g + k];
        if (KC == 4) {
          float v0 = bflo(b[k].x), v1 = bfhi(b[k].x), v2 = bflo(b[k].y), v3 = bfhi(b[k].y);
          acc[0][0] += w.x * v0; acc[0][1] += w.x * v1; acc[0][2] += w.x * v2; acc[0][3] += w.x * v3;
          acc[1][0] += w.y * v0; acc[1][1] += w.y * v1; acc[1][2] += w.y * v2; acc[1][3] += w.y * v3;
          acc[2][0] += w.z * v0; acc[2][1] += w.z * v1; acc[2][2] += w.z * v2; acc[2][3] += w.z * v3;
          acc[3][0] += w.w * v0; acc[3][1] += w.w * v1; acc[3][2] += w.w * v2; acc[3][3] += w.w * v3;
        } else {
          float v0 = bflo(b[k].x), v1 = bfhi(b[k].x);
          acc[0][0] += w.x * v0; acc[0][1] += w.x * v1;
          acc[1][0] += w.y * v0; acc[1][1] += w.y * v1;
          acc[2][0] += w.z * v0; acc[2][1] += w.z * v1;
          acc[3][0] += w.w * v0; acc[3][1] += w.w * v1;
        }
      }
    };
    loadb(0, bA);
    int i = 0;
    while (i + 2 <= nb) {
      loadb((i + 1) * 8, bB);
      fmab(i * 8, bA);
      if (i + 2 < nb) loadb((i + 2) * 8, bA);
      fmab((i + 1) * 8, bB);
      i += 2;
    }
    if (i < nb) fmab(i * 8, bA);
  } else {
    float m0 = -1e30f, m1 = -1e30f, m2 = -1e30f, m3 = -1e30f;
    for (int i = r0 + lane; i < r1; i += 64) {
      const float4 av = *(const float4*)&asad[(size_t)col[i] * 8];
      m0 = fmaxf(m0, lrelu(av.x + adv.x)); m1 = fmaxf(m1, lrelu(av.y + adv.y));
      m2 = fmaxf(m2, lrelu(av.z + adv.z)); m3 = fmaxf(m3, lrelu(av.w + adv.w));
    }
#pragma unroll
    for (int d = 1; d < 64; d <<= 1) {
      m0 = fmaxf(m0, __shfl_xor(m0, d)); m1 = fmaxf(m1, __shfl_xor(m1, d));
      m2 = fmaxf(m2, __shfl_xor(m2, d)); m3 = fmaxf(m3, __shfl_xor(m3, d));
    }
    float d0 = 0.f, d1 = 0.f, d2 = 0.f, d3 = 0.f;
    for (int i = r0 + lane; i < r1; i += 64) {
      const float4 av = *(const float4*)&asad[(size_t)col[i] * 8];
      d0 += __expf(lrelu(av.x + adv.x) - m0); d1 += __expf(lrelu(av.y + adv.y) - m1);
      d2 += __expf(lrelu(av.z + adv.z) - m2); d3 += __expf(lrelu(av.w + adv.w) - m3);
    }
#pragma unroll
    for (int d = 1; d < 64; d <<= 1) {
      d0 += __shfl_xor(d0, d); d1 += __shfl_xor(d1, d);
      d2 += __shfl_xor(d2, d); d3 += __shfl_xor(d3, d);
    }
    const float i0 = 1.f / (d0 + 1e-16f), i1 = 1.f / (d1 + 1e-16f);
    const float i2 = 1.f / (d2 + 1e-16f), i3 = 1.f / (d3 + 1e-16f);
    for (int base = r0; base < r1; base += 64) {
      const int ne = min(64, r1 - base);
      if (lane < ne) {
        const int s = col[base + lane];
        const float4 av = *(const float4*)&asad[(size_t)s * 8];
        sb[wv][lane] = s * (K * 2);
        wl[wv][lane] = make_float4(__expf(lrelu(av.x + adv.x) - m0) * i0,
                                   __expf(lrelu(av.y + adv.y) - m1) * i1,
                                   __expf(lrelu(av.z + adv.z) - m2) * i2,
                                   __expf(lrelu(av.w + adv.w) - m3) * i3);
      }
      __builtin_amdgcn_wave_barrier();
      for (int g = 0; g < ne; ++g)
        edge_fma(fb + (size_t)sb[wv][g] + loff, wl[wv][g]);
      __builtin_amdgcn_wave_barrier();
    }
  }

#pragma unroll
  for (int j = 0; j < 4; ++j) {
    if (KC == 4) {
      uint2 ov;
      ov.x = pack2bf(acc[j][0], acc[j][1]);
      ov.y = pack2bf(acc[j][2], acc[j][3]);
      *(uint2*)&agg[(size_t)n * (4 * K) + j * K + lane * 4] = ov;
    } else {
      *(uint32_t*)&agg[(size_t)n * (4 * K) + j * K + lane * 2] = pack2bf(acc[j][0], acc[j][1]);
    }
  }
}

// ---------------- input-space GAT aggregation, H=1 (K=128): 2 nodes/block ------------

__global__ __launch_bounds__(128) void gat_agg_in1(const bf16_t* __restrict__ f,
                                                   const float* __restrict__ asad,
                                                   const int* __restrict__ cnt,
                                                   const int* __restrict__ col,
                                                   bf16_t* __restrict__ agg) {
  const int wv = threadIdx.x >> 6, lane = threadIdx.x & 63;
  const int n = blockIdx.x * 2 + wv;
  __shared__ int sb[2][64];
  __shared__ float wl[2][64];

  const int r0 = n * CAP;
  const int deg = cnt[n];
  const int r1 = r0 + deg;
  const float adv = asad[(size_t)n * 2 + 1];
  const char* fb = (const char*)f;
  const size_t loff = (size_t)lane * 4;
  float a0 = 0.f, a1 = 0.f;

  auto fma2 = [&](uint32_t v, float w) { a0 += w * bflo(v); a1 += w * bfhi(v); };

  if (deg <= 64) {
    const bool valid = lane < deg;
    int s = n;  // invalid lanes: self row, weight 0
    float e = -1e30f;
    if (valid) { s = col[r0 + lane]; e = lrelu(asad[(size_t)s * 2] + adv); }
    float m = e;
#pragma unroll
    for (int d = 1; d < 64; d <<= 1) m = fmaxf(m, __shfl_xor(m, d));
    float x = valid ? __expf(e - m) : 0.f;
    float den = x;
#pragma unroll
    for (int d = 1; d < 64; d <<= 1) den += __shfl_xor(den, d);
    sb[wv][lane] = s * 256;
    wl[wv][lane] = valid ? x / (den + 1e-16f) : 0.f;
    __builtin_amdgcn_wave_barrier();

    const int nb = (deg + 7) >> 3;
    uint32_t bA[8], bB[8];
    auto loadb = [&](int g, uint32_t* b) {
#pragma unroll
      for (int k = 0; k < 8; ++k)
        b[k] = *(const uint32_t*)(fb + (size_t)sb[wv][g + k] + loff);
    };
    auto fmab = [&](int g, const uint32_t* b) {
#pragma unroll
      for (int k = 0; k < 8; ++k) {
        const float w = wl[wv][g + k];
        a0 += w * bflo(b[k]); a1 += w * bfhi(b[k]);
      }
    };
    loadb(0, bA);
    int i = 0;
    while (i + 2 <= nb) {
      loadb((i + 1) * 8, bB);
      fmab(i * 8, bA);
      if (i + 2 < nb) loadb((i + 2) * 8, bA);
      fmab((i + 1) * 8, bB);
      i += 2;
    }
    if (i < nb) fmab(i * 8, bA);
  } else {
    float m = -1e30f;
    for (int i = r0 + lane; i < r1; i += 64) m = fmaxf(m, lrelu(asad[(size_t)col[i] * 2] + adv));
#pragma unroll
    for (int d = 1; d < 64; d <<= 1) m = fmaxf(m, __shfl_xor(m, d));
    float den = 0.f;
    for (int i = r0 + lane; i < r1; i += 64) den += __expf(lrelu(asad[(size_t)col[i] * 2] + adv) - m);
#pragma unroll
    for (int d = 1; d < 64; d <<= 1) den += __shfl_xor(den, d);
    const float dinv = 1.f / (den + 1e-16f);
    for (int base = r0; base < r1; base += 64) {
      const int ne = min(64, r1 - base);
      if (lane < ne) {
        const int s = col[base + lane];
        sb[wv][lane] = s * 256;
        wl[wv][lane] = __expf(lrelu(asad[(size_t)s * 2] + adv) - m) * dinv;
      }
      __builtin_amdgcn_wave_barrier();
      for (int g = 0; g < ne; ++g)
        fma2(*(const uint32_t*)(fb + (size_t)sb[wv][g] + loff), wl[wv][g]);
      __builtin_amdgcn_wave_barrier();
    }
  }
  *(uint32_t*)&agg[(size_t)n * 128 + lane * 2] = pack2bf(a0, a1);
}

// ---------------- fused classifier tail (FROZEN: exact known-pass bytes) ----------------
// Empirically threshold-sensitive to restructuring (R7/R8 failures) -> do not modify.

__global__ __launch_bounds__(256) void mlp_tail(const bf16_t* __restrict__ A,
                                                const bf16_t* __restrict__ M3t,
                                                const float* __restrict__ bm,
                                                const bf16_t* __restrict__ l2t,
                                                const float* __restrict__ l2b,
                                                const bf16_t* __restrict__ l3t,
                                                const float* __restrict__ l3b,
                                                float* __restrict__ out, int M) {
  __shared__ __align__(16) bf16_t As[128 * 128];
  __shared__ __align__(16) bf16_t Ws[128 * 128];
  const int t = threadIdx.x, wave = t >> 6, lane = t & 63;
  const int ln15 = lane & 15, quad = lane >> 4;
  const int bmr = blockIdx.x * 128;
  const int rowLim = M - 1 - bmr;

#pragma unroll
  for (int r = 0; r < 8; ++r) {
    int base = (wave * 8 + r) * 1024;
    int flat = base + lane * 16;
    int row = flat >> 8;
    int grow = row < rowLim ? row : rowLim;
    const char* gp = (const char*)A + (size_t)grow * 256 + (flat & 255);
    __builtin_amdgcn_global_load_lds((const AS1 void*)gp,
                                     (AS3 void*)((char*)As + base), 16, 0, 0);
  }
#pragma unroll
  for (int r = 0; r < 8; ++r) {
    int base = (wave * 8 + r) * 1024;
    __builtin_amdgcn_global_load_lds((const AS1 void*)((const char*)M3t + base + lane * 16),
                                     (AS3 void*)((char*)Ws + base), 16, 0, 0);
  }
  __syncthreads();

  const int wm = wave * 32;
  f32x4 a1[2][8];
#pragma unroll
  for (int mi = 0; mi < 2; ++mi)
#pragma unroll
    for (int ni = 0; ni < 8; ++ni) a1[mi][ni] = (f32x4){0.f, 0.f, 0.f, 0.f};
#pragma unroll
  for (int kk = 0; kk < 128; kk += 32) {
    bf16x8 af[2];
#pragma unroll
    for (int mi = 0; mi < 2; ++mi)
      af[mi] = *(const bf16x8*)&As[(wm + mi * 16 + ln15) * 128 + kk + quad * 8];
#pragma unroll
    for (int ni = 0; ni < 8; ++ni) {
      bf16x8 bf = *(const bf16x8*)&Ws[(ni * 16 + ln15) * 128 + kk + quad * 8];
#pragma unroll
      for (int mi = 0; mi < 2; ++mi)
        a1[mi][ni] = __builtin_amdgcn_mfma_f32_16x16x32_bf16(af[mi], bf, a1[mi][ni], 0, 0, 0);
    }
  }
  __syncthreads();

#pragma unroll
  for (int r = 0; r < 4; ++r) {
    int base = (wave * 4 + r) * 1024;
    __builtin_amdgcn_global_load_lds((const AS1 void*)((const char*)l2t + base + lane * 16),
                                     (AS3 void*)((char*)Ws + base), 16, 0, 0);
  }
#pragma unroll
  for (int r = 0; r < 2; ++r) {
    int base = (wave * 2 + r) * 1024;
    __builtin_amdgcn_global_load_lds((const AS1 void*)((const char*)l3t + base + lane * 16),
                                     (AS3 void*)((char*)Ws + 8192 * 2 + base), 16, 0, 0);
  }
#pragma unroll
  for (int mi = 0; mi < 2; ++mi) {
    int r0 = wm + mi * 16 + quad * 4;
#pragma unroll
    for (int ni = 0; ni < 8; ++ni) {
      int c = ni * 16 + ln15;
      float bv = bm[c];
#pragma unroll
      for (int reg = 0; reg < 4; ++reg)
        As[(r0 + reg) * 128 + c] = (bf16_t)fmaxf(a1[mi][ni][reg] + bv, 0.f);
    }
  }
  __syncthreads();

  f32x4 a2[2][4];
#pragma unroll
  for (int mi = 0; mi < 2; ++mi)
#pragma unroll
    for (int ni = 0; ni < 4; ++ni) a2[mi][ni] = (f32x4){0.f, 0.f, 0.f, 0.f};
#pragma unroll
  for (int kk = 0; kk < 128; kk += 32) {
    bf16x8 af[2];
#pragma unroll
    for (int mi = 0; mi < 2; ++mi)
      af[mi] = *(const bf16x8*)&As[(wm + mi * 16 + ln15) * 128 + kk + quad * 8];
#pragma unroll
    for (int ni = 0; ni < 4; ++ni) {
      bf16x8 bf = *(const bf16x8*)&Ws[(ni * 16 + ln15) * 128 + kk + quad * 8];
#pragma unroll
      for (int mi = 0; mi < 2; ++mi)
        a2[mi][ni] = __builtin_amdgcn_mfma_f32_16x16x32_bf16(af[mi], bf, a2[mi][ni], 0, 0, 0);
    }
  }
  __syncthreads();

#pragma unroll
  for (int mi = 0; mi < 2; ++mi) {
    int r0 = wm + mi * 16 + quad * 4;
#pragma unroll
    for (int ni = 0; ni < 4; ++ni) {
      int c = ni * 16 + ln15;
      float bv = l2b[c];
#pragma unroll
      for (int reg = 0; reg < 4; ++reg)
        As[(r0 + reg) * 64 + c] = (bf16_t)fmaxf(a2[mi][ni][reg] + bv, 0.f);
    }
  }
  __syncthreads();

  f32x4 a3[2][4];
#pragma unroll
  for (int mi = 0; mi < 2; ++mi)
#pragma unroll
    for (int ni = 0; ni < 4; ++ni) a3[mi][ni] = (f32x4){0.f, 0.f, 0.f, 0.f};
#pragma unroll
  for (int kk = 0; kk < 64; kk += 32) {
    bf16x8 af[2];
#pragma unroll
    for (int mi = 0; mi < 2; ++mi)
      af[mi] = *(const bf16x8*)&As[(wm + mi * 16 + ln15) * 64 + kk + quad * 8];
#pragma unroll
    for (int ni = 0; ni < 4; ++ni) {
      bf16x8 bf = *(const bf16x8*)&Ws[8192 + (ni * 16 + ln15) * 64 + kk + quad * 8];
#pragma unroll
      for (int mi = 0; mi < 2; ++mi)
        a3[mi][ni] = __builtin_amdgcn_mfma_f32_16x16x32_bf16(af[mi], bf, a3[mi][ni], 0, 0, 0);
    }
  }
#pragma unroll
  for (int mi = 0; mi < 2; ++mi) {
    int r0 = wm + mi * 16 + quad * 4;
#pragma unroll
    for (int ni = 0; ni < 4; ++ni) {
      int c = ni * 16 + ln15;
      float bv = l3b[c];
#pragma unroll
      for (int reg = 0; reg < 4; ++reg) {
        int r = bmr + r0 + reg;
        if (r < M) {
          float v = a3[mi][ni][reg] + bv;
          out[(size_t)r * 64 + c] = 1.f / (1.f + __expf(-v));
        }
      }
    }
  }
}

// ---------------- launch ----------------

extern "C" void kernel_launch(void* const* d_in, const int* in_sizes, int n_in,
                              void* d_out, int out_size, void* d_ws, size_t ws_size,
                              hipStream_t stream) {
  const float* x      = (const float*)d_in[0];
  const int*   ei     = (const int*)d_in[1];
  const float* W1     = (const float*)d_in[2];
  const float* a_src1 = (const float*)d_in[3];
  const float* a_dst1 = (const float*)d_in[4];
  const float* b1     = (const float*)d_in[5];
  const float* W2     = (const float*)d_in[6];
  const float* a_src2 = (const float*)d_in[7];
  const float* a_dst2 = (const float*)d_in[8];
  const float* b2     = (const float*)d_in[9];
  const float* W3     = (const float*)d_in[10];
  const float* a_src3 = (const float*)d_in[11];
  const float* a_dst3 = (const float*)d_in[12];
  const float* b3     = (const float*)d_in[13];
  const float* bn1g = (const float*)d_in[14];
  const float* bn1b = (const float*)d_in[15];
  const float* bn1m = (const float*)d_in[16];
  const float* bn1v = (const float*)d_in[17];
  const float* bn2g = (const float*)d_in[18];
  const float* bn2b = (const float*)d_in[19];
  const float* bn2m = (const float*)d_in[20];
  const float* bn2v = (const float*)d_in[21];
  const float* l1w = (const float*)d_in[22];
  const float* l1b = (const float*)d_in[23];
  const float* l2w = (const float*)d_in[24];
  const float* l2b = (const float*)d_in[25];
  const float* l3w = (const float*)d_in[26];
  const float* l3b = (const float*)d_in[27];
  float* out = (float*)d_out;

  const int N = NN;
  const int E = in_sizes[1] / 2;
  const int ET = E + N;
  const int EB = (ET + 255) / 256;

  char* p = (char*)d_ws;
  auto carve = [&](size_t bytes) {
    char* q = p;
    p += (bytes + 255) & ~(size_t)255;
    return q;
  };
  bf16_t* xb    = (bf16_t*)carve((size_t)N * 256 * 2);
  bf16_t* aggb  = (bf16_t*)carve((size_t)N * 1024 * 2);
  bf16_t* f1b   = (bf16_t*)carve((size_t)N * 128 * 2);
  bf16_t* f2b   = (bf16_t*)carve((size_t)N * 128 * 2);
  float* asadA  = (float*)carve((size_t)N * 8 * 4);
  // zero-group: cnt + asadB + asadC cleared by ONE memset
  int* cnt      = (int*)carve((size_t)N * 4);
  float* asadB  = (float*)carve((size_t)N * 8 * 4);
  float* asadC  = (float*)carve((size_t)N * 2 * 4);
  const size_t zbytes = (size_t)(p - (char*)cnt);
  int* col      = (int*)carve((size_t)N * CAP * 4);
  bf16_t* Ws1t  = (bf16_t*)carve((size_t)128 * 1024 * 2);
  bf16_t* Ws2t  = (bf16_t*)carve((size_t)128 * 512 * 2);
  bf16_t* M3t   = (bf16_t*)carve((size_t)128 * 128 * 2);
  bf16_t* l2t   = (bf16_t*)carve((size_t)64 * 128 * 2);
  bf16_t* l3t   = (bf16_t*)carve((size_t)64 * 64 * 2);
  float* P1     = (float*)carve((size_t)8 * 256 * 4);
  float* P2     = (float*)carve((size_t)8 * 128 * 4);
  float* P3     = (float*)carve((size_t)2 * 128 * 4);
  float* bm     = (float*)carve((size_t)128 * 4);
  (void)ws_size; (void)n_in; (void)out_size;

  hipMemsetAsync(cnt, 0, zbytes, stream);

  Prep1Args pa;
  pa.wp.d[0] = {W1,  Ws1t, 256, 128, 4, 0.25f, 0};
  pa.wp.d[1] = {W2,  Ws2t, 128, 128, 4, 0.25f, 128};
  pa.wp.d[2] = {l2w, l2t,  128, 64,  1, 1.0f,  192};
  pa.wp.d[3] = {l3w, l3t,  64,  64,  1, 1.0f,  200};
  pa.W1 = W1; pa.as1 = a_src1; pa.ad1 = a_dst1;
  pa.W2 = W2; pa.as2 = a_src2; pa.ad2 = a_dst2;
  pa.W3 = W3; pa.as3 = a_src3; pa.ad3 = a_dst3;
  pa.P1 = P1; pa.P2 = P2; pa.P3 = P3;
  pa.W3m = W3; pa.L1w = l1w; pa.b3v = b3; pa.l1b = l1b;
  pa.M3t = M3t; pa.bm = bm;
  pa.ei = ei; pa.E = E; pa.N = N; pa.EB = EB;
  pa.cnt = cnt; pa.col = col;
  prep1<<<780 + EB, 256, 0, stream>>>(pa);

  // separate launch: consumes P1 produced by prep1 (kernel boundary = ordering)
  cast_alpha<<<N / 4, 256, 0, stream>>>(x, P1, xb, asadA);

  const int gm32 = (N + 31) / 32;   // 625 row-tiles for the TM=32 GEMM
  const int gm   = (N + 127) / 128; // 157 row-tiles for mlp_tail
  const int gb   = N / 2;           // 10000 gather blocks (2 nodes each)

  // --- GAT layer 1 (GEMM epilogue also emits layer-2 alpha logits) ---
  gat_agg_in4<256><<<gb, 128, 0, stream>>>(xb, asadA, cnt, col, aggb);
  gemm_mfma<3, 8, bf16_t><<<dim3(gm32, 1), 256, 0, stream>>>(
      aggb, Ws1t, b1, bn1g, bn1b, bn1m, bn1v, f1b, P2, asadB, N, 128, 1024);

  // --- GAT layer 2 (GEMM epilogue emits layer-3 alpha logits) ---
  gat_agg_in4<128><<<gb, 128, 0, stream>>>(f1b, asadB, cnt, col, aggb);
  gemm_mfma<3, 2, bf16_t><<<dim3(gm32, 1), 256, 0, stream>>>(
      aggb, Ws2t, b2, bn2g, bn2b, bn2m, bn2v, f2b, P3, asadC, N, 128, 512);

  // --- GAT layer 3 (H=1) + fused classifier tail ---
  gat_agg_in1<<<gb, 128, 0, stream>>>(f2b, asadC, cnt, col, aggb);
  mlp_tail<<<gm, 256, 0, stream>>>(aggb, M3t, bm, l2t, l2b, l3t, l3b, out, N);
}

// Round 13
// 271.802 us; speedup vs baseline: 1.1434x; 1.0392x over previous
//
#include <hip/hip_runtime.h>
#include <cstdint>
#include <cstddef>

#define NN 20000
#define CAP 96

typedef __bf16 bf16_t;
typedef __bf16 bf16x8 __attribute__((ext_vector_type(8)));
typedef float f32x4 __attribute__((ext_vector_type(4)));

#define AS1 __attribute__((address_space(1)))
#define AS3 __attribute__((address_space(3)))

__device__ __forceinline__ float lrelu(float x) { return x >= 0.f ? x : 0.2f * x; }
__device__ __forceinline__ float bflo(uint32_t u) { return __uint_as_float(u << 16); }
__device__ __forceinline__ float bfhi(uint32_t u) { return __uint_as_float(u & 0xffff0000u); }

__device__ __forceinline__ uint32_t pack2bf(float a, float b) {
  bf16_t x = (bf16_t)a, y = (bf16_t)b;
  uint16_t ux = __builtin_bit_cast(uint16_t, x);
  uint16_t uy = __builtin_bit_cast(uint16_t, y);
  return (uint32_t)ux | ((uint32_t)uy << 16);
}

// ---------------- prep mega-kernel ----------------
// block ranges: [0,204) wprep | [204,716) alpha_proj | [716,780) merge_w3l1
//             | [780,780+EB) scatter
// NOTE: no block in this launch may READ an output produced by another block
// of this same launch (no intra-launch ordering). P1 consumers live in
// cast_alpha, a separate kernel.

struct WDesc { const float* W; bf16_t* Bt; int K; int Cw; int H; float scale; int b0; };
struct WPack { WDesc d[4]; };

struct Prep1Args {
  WPack wp;
  const float *W1, *as1, *ad1, *W2, *as2, *ad2, *W3, *as3, *ad3;
  float *P1, *P2, *P3;
  const float *W3m, *L1w, *b3v, *l1b;
  bf16_t* M3t; float* bm;
  const int* ei; int E, N, EB;
  int* cnt; int* col;
};

__global__ __launch_bounds__(256) void prep1(Prep1Args a) {
  __shared__ float tile[32][33];
  const int b = blockIdx.x;
  const int t = threadIdx.x;

  if (b < 204) {
    int i = 3;
#pragma unroll
    for (int k = 2; k >= 0; --k)
      if (b < a.wp.d[k + 1].b0) i = k;
    const WDesc de = a.wp.d[i];
    const int bi = b - de.b0;
    const int ktiles = de.K / 32;
    const int kt = bi % ktiles, rt = bi / ktiles;
    const int gc = rt * 32;
    const int h = gc / de.Cw, c0 = gc % de.Cw;
    const int tx = t & 31, ty = t >> 5;
#pragma unroll
    for (int r = 0; r < 32; r += 8)
      tile[ty + r][tx] = de.W[(size_t)(kt * 32 + ty + r) * (de.H * de.Cw) + h * de.Cw + c0 + tx];
    __syncthreads();
#pragma unroll
    for (int r = 0; r < 32; r += 8)
      de.Bt[(size_t)(c0 + ty + r) * (de.H * de.K) + h * de.K + kt * 32 + tx] =
          (bf16_t)(de.scale * tile[tx][ty + r]);
  } else if (b < 716) {
    const int kk = b - 204;
    const float *W, *asrc, *adst;
    float* P;
    int K, H, k;
    if (kk < 256)      { W = a.W1; asrc = a.as1; adst = a.ad1; P = a.P1; K = 256; H = 4; k = kk; }
    else if (kk < 384) { W = a.W2; asrc = a.as2; adst = a.ad2; P = a.P2; K = 128; H = 4; k = kk - 256; }
    else               { W = a.W3; asrc = a.as3; adst = a.ad3; P = a.P3; K = 128; H = 1; k = kk - 384; }
    for (int j = 0; j < 2 * H; ++j) {
      const int h = (j < H) ? j : j - H;
      const float* av = (j < H) ? asrc : adst;
      float pv = 0.f;
      if (t < 128) pv = W[(size_t)k * (H * 128) + h * 128 + t] * av[h * 128 + t];
#pragma unroll
      for (int d = 1; d < 64; d <<= 1) pv += __shfl_xor(pv, d);
      if (t == 0 || t == 64) tile[0][t >> 6] = pv;
      __syncthreads();
      if (t == 0) P[j * K + k] = tile[0][0] + tile[0][1];
      __syncthreads();
    }
  } else if (b < 780) {
    const int idx = (b - 716) * 256 + t;
    const int k = idx >> 7, c = idx & 127;
    float s = 0.f;
    for (int m = 0; m < 128; ++m) s += a.W3m[k * 128 + m] * a.L1w[m * 128 + c];
    a.M3t[c * 128 + k] = (bf16_t)s;
    if (k == 0) {
      float tt = a.l1b[c];
      for (int m = 0; m < 128; ++m) tt += a.b3v[m] * a.L1w[m * 128 + c];
      a.bm[c] = tt;
    }
  } else {
    // direct bucket scatter: replaces hist + scan + cursor-scatter
    const int i = (b - 780) * 256 + t;
    if (i < a.E + a.N) {
      int src, dst;
      if (i < a.E) { src = a.ei[i]; dst = a.ei[a.E + i]; }
      else         { src = i - a.E; dst = src; }
      int slot = atomicAdd(&a.cnt[dst], 1);
      a.col[(size_t)dst * CAP + slot] = src;
    }
  }
}

// ---------------- fused cast + layer-1 alpha (separate launch: consumes P1) ----------

__global__ __launch_bounds__(256) void cast_alpha(const float* __restrict__ x,
                                                  const float* __restrict__ P1,
                                                  bf16_t* __restrict__ xb,
                                                  float* __restrict__ asadA) {
  const int b = blockIdx.x, t = threadIdx.x;
  const int wv = t >> 6, lane = t & 63;
  const int n = b * 4 + wv;
  const float4 v = *(const float4*)&x[(size_t)n * 256 + lane * 4];
  uint2 ov;
  ov.x = pack2bf(v.x, v.y);
  ov.y = pack2bf(v.z, v.w);
  *(uint2*)&xb[(size_t)n * 256 + lane * 4] = ov;
  float s[8];
#pragma unroll
  for (int j = 0; j < 8; ++j) {
    const float4 pj = *(const float4*)&P1[j * 256 + lane * 4];
    s[j] = v.x * pj.x + v.y * pj.y + v.z * pj.z + v.w * pj.w;
  }
#pragma unroll
  for (int j = 0; j < 8; ++j)
#pragma unroll
    for (int d = 1; d < 64; d <<= 1) s[j] += __shfl_xor(s[j], d);
  if (lane == 0) {
#pragma unroll
    for (int j = 0; j < 8; ++j) asadA[(size_t)n * 8 + j] = s[j];
  }
}

// ---------------- bf16 MFMA GEMM: C = act(A @ Bt^T + bias) ----------------
// TM=32 x TN=128: 625 blocks (~2.4/CU). A panel read once. LDS XOR-swizzled.
// Alpha epilogue: TN spans full N, so each row's logit has exactly 2 wave
// contributions -> combine via LDS + plain store (bit-identical to the old
// 2x atomicAdd: two-term f32 addition commutes exactly). asad needs no memset.
// ACT: 1=relu, 3=BN(eval)+relu

template <int ACT, int J, typename OUT_T>
__global__ __launch_bounds__(256) void gemm_mfma(const bf16_t* __restrict__ A,
                                                 const bf16_t* __restrict__ Bt,
                                                 const float* __restrict__ bias,
                                                 const float* __restrict__ bng,
                                                 const float* __restrict__ bnb,
                                                 const float* __restrict__ bnm,
                                                 const float* __restrict__ bnv,
                                                 OUT_T* __restrict__ C,
                                                 const float* __restrict__ Pa,
                                                 float* __restrict__ asad,
                                                 int M, int N, int K) {
  constexpr int TM = 32, TN = 128, BK = 64;
  constexpr int NRA = (TM * BK * 2) / 4096;  // 1
  constexpr int NRB = (TN * BK * 2) / 4096;  // 4
  __shared__ __align__(16) bf16_t As[TM * BK];
  __shared__ __align__(16) bf16_t Bs[TN * BK];
  __shared__ float part[2][TM][8];

  const int t = threadIdx.x;
  const int wave = t >> 6, lane = t & 63;
  const int ln15 = lane & 15, quad = lane >> 4;
  const int bm = blockIdx.x * TM;
  const int wm = (wave >> 1) * 16;   // 2 wave-rows x 16 rows
  const int wn = (wave & 1) * 64;    // 2 wave-cols x 64 cols
  const int rowLimA = M - 1 - bm;
  const size_t strideAB = (size_t)K * 2;

  f32x4 acc[4];
#pragma unroll
  for (int ni = 0; ni < 4; ++ni) acc[ni] = (f32x4){0.f, 0.f, 0.f, 0.f};

  const char* gA = (const char*)(A + (size_t)bm * K);
  const char* gB = (const char*)Bt;

  for (int k0 = 0; k0 < K; k0 += BK) {
#pragma unroll
    for (int r = 0; r < NRA; ++r) {
      int base = (wave * NRA + r) * 1024;
      int flat = base + lane * 16;
      int row = flat >> 7;
      int grow = row < rowLimA ? row : rowLimA;
      int colS = (flat & 127) ^ ((row & 7) << 4);  // pre-swizzled source column
      const char* gp = gA + (size_t)grow * strideAB + (size_t)(k0 * 2) + colS;
      __builtin_amdgcn_global_load_lds((const AS1 void*)gp,
                                       (AS3 void*)((char*)As + base), 16, 0, 0);
    }
#pragma unroll
    for (int r = 0; r < NRB; ++r) {
      int base = (wave * NRB + r) * 1024;
      int flat = base + lane * 16;
      int row = flat >> 7;
      int colS = (flat & 127) ^ ((row & 7) << 4);  // pre-swizzled source column
      const char* gp = gB + (size_t)row * strideAB + (size_t)(k0 * 2) + colS;
      __builtin_amdgcn_global_load_lds((const AS1 void*)gp,
                                       (AS3 void*)((char*)Bs + base), 16, 0, 0);
    }
    __syncthreads();
#pragma unroll
    for (int kk = 0; kk < BK; kk += 32) {
      bf16x8 af, bfr[4];
      {
        const int arow = wm + ln15;
        unsigned abyte = (unsigned)(arow * 128 + (kk + quad * 8) * 2) ^
                         (unsigned)((arow & 7) << 4);
        af = *(const bf16x8*)((const char*)As + abyte);
      }
#pragma unroll
      for (int ni = 0; ni < 4; ++ni) {
        const int brow = wn + ni * 16 + ln15;
        unsigned bbyte = (unsigned)(brow * 128 + (kk + quad * 8) * 2) ^
                         (unsigned)((brow & 7) << 4);
        bfr[ni] = *(const bf16x8*)((const char*)Bs + bbyte);
      }
#pragma unroll
      for (int ni = 0; ni < 4; ++ni)
        acc[ni] = __builtin_amdgcn_mfma_f32_16x16x32_bf16(af, bfr[ni], acc[ni], 0, 0, 0);
    }
    __syncthreads();
  }

  {
    int r0 = bm + wm + quad * 4;
#pragma unroll
    for (int ni = 0; ni < 4; ++ni) {
      int c = wn + ni * 16 + ln15;
      float bv = bias ? bias[c] : 0.f;
      float sc = 1.f, sh = 0.f;
      if (ACT == 3) {
        sc = bng[c] * rsqrtf(bnv[c] + 1e-5f);
        sh = bnb[c] - bnm[c] * sc;
      }
#pragma unroll
      for (int reg = 0; reg < 4; ++reg) {
        int r = r0 + reg;
        float v = acc[ni][reg] + bv;
        if (ACT == 1) v = fmaxf(v, 0.f);
        else if (ACT == 3) v = fmaxf(v * sc + sh, 0.f);
        acc[ni][reg] = v;  // stash post-activation value for alpha epilogue
        if (r < M) C[(size_t)r * N + c] = (OUT_T)v;
      }
    }
  }

  if (J > 0) {
#pragma unroll
    for (int j = 0; j < J; ++j) {
      float pj[4];
#pragma unroll
      for (int ni = 0; ni < 4; ++ni)
        pj[ni] = Pa[j * 128 + wn + ni * 16 + ln15];
      float s[4];
#pragma unroll
      for (int reg = 0; reg < 4; ++reg)
        s[reg] = acc[0][reg] * pj[0] + acc[1][reg] * pj[1] +
                 acc[2][reg] * pj[2] + acc[3][reg] * pj[3];
#pragma unroll
      for (int d = 1; d < 16; d <<= 1)
#pragma unroll
        for (int reg = 0; reg < 4; ++reg)
          s[reg] += __shfl_xor(s[reg], d);
      if (ln15 == 0) {
#pragma unroll
        for (int reg = 0; reg < 4; ++reg)
          part[wave & 1][wm + quad * 4 + reg][j] = s[reg];
      }
    }
    __syncthreads();
    if ((wave & 1) == 0 && ln15 == 0) {
#pragma unroll
      for (int j = 0; j < J; ++j)
#pragma unroll
        for (int reg = 0; reg < 4; ++reg) {
          int rl = wm + quad * 4 + reg;
          int r = bm + rl;
          if (r < M) asad[(size_t)r * J + j] = part[0][rl][j] + part[1][rl][j];
        }
    }
  }
}

// ---------------- input-space GAT aggregation, H=4: wave/node, 2 nodes/block ---------
// Edge loop: padded full 8-edge batches (invalid lanes carry weight 0 and point at
// the node's own row), two-deep ping-pong prefetch of the gathered rows.

template <int K>
__global__ __launch_bounds__(128) void gat_agg_in4(const bf16_t* __restrict__ f,
                                                   const float* __restrict__ asad,
                                                   const int* __restrict__ cnt,
                                                   const int* __restrict__ col,
                                                   bf16_t* __restrict__ agg) {
  constexpr int KC = K / 64;
  const int wv = threadIdx.x >> 6, lane = threadIdx.x & 63;
  const int n = blockIdx.x * 2 + wv;
  __shared__ int sb[2][64];
  __shared__ float4 wl[2][64];

  const int r0 = n * CAP;
  const int deg = cnt[n];
  const int r1 = r0 + deg;
  const float4 adv = *(const float4*)&asad[(size_t)n * 8 + 4];
  const char* fb = (const char*)f;
  const size_t loff = (size_t)lane * (KC * 2);

  float acc[4][KC];
#pragma unroll
  for (int j = 0; j < 4; ++j)
#pragma unroll
    for (int q = 0; q < KC; ++q) acc[j][q] = 0.f;

  auto edge_fma = [&](const char* gp, float4 w4) {
    if (KC == 4) {
      uint2 b = *(const uint2*)gp;
      float v0 = bflo(b.x), v1 = bfhi(b.x), v2 = bflo(b.y), v3 = bfhi(b.y);
      acc[0][0] += w4.x * v0; acc[0][1] += w4.x * v1; acc[0][2] += w4.x * v2; acc[0][3] += w4.x * v3;
      acc[1][0] += w4.y * v0; acc[1][1] += w4.y * v1; acc[1][2] += w4.y * v2; acc[1][3] += w4.y * v3;
      acc[2][0] += w4.z * v0; acc[2][1] += w4.z * v1; acc[2][2] += w4.z * v2; acc[2][3] += w4.z * v3;
      acc[3][0] += w4.w * v0; acc[3][1] += w4.w * v1; acc[3][2] += w4.w * v2; acc[3][3] += w4.w * v3;
    } else {
      uint32_t b = *(const uint32_t*)gp;
      float v0 = bflo(b), v1 = bfhi(b);
      acc[0][0] += w4.x * v0; acc[0][1] += w4.x * v1;
      acc[1][0] += w4.y * v0; acc[1][1] += w4.y * v1;
      acc[2][0] += w4.z * v0; acc[2][1] += w4.z * v1;
      acc[3][0] += w4.w * v0; acc[3][1] += w4.w * v1;
    }
  };

  if (deg <= 64) {
    const bool valid = lane < deg;
    int s = n;  // invalid lanes: self row (safe address), weight 0
    float e0 = -1e30f, e1 = -1e30f, e2 = -1e30f, e3 = -1e30f;
    if (valid) {
      s = col[r0 + lane];
      const float4 av = *(const float4*)&asad[(size_t)s * 8];
      e0 = lrelu(av.x + adv.x); e1 = lrelu(av.y + adv.y);
      e2 = lrelu(av.z + adv.z); e3 = lrelu(av.w + adv.w);
    }
    float m0 = e0, m1 = e1, m2 = e2, m3 = e3;
#pragma unroll
    for (int d = 1; d < 64; d <<= 1) {
      m0 = fmaxf(m0, __shfl_xor(m0, d)); m1 = fmaxf(m1, __shfl_xor(m1, d));
      m2 = fmaxf(m2, __shfl_xor(m2, d)); m3 = fmaxf(m3, __shfl_xor(m3, d));
    }
    float x0 = valid ? __expf(e0 - m0) : 0.f;
    float x1 = valid ? __expf(e1 - m1) : 0.f;
    float x2 = valid ? __expf(e2 - m2) : 0.f;
    float x3 = valid ? __expf(e3 - m3) : 0.f;
    float d0 = x0, d1 = x1, d2 = x2, d3 = x3;
#pragma unroll
    for (int d = 1; d < 64; d <<= 1) {
      d0 += __shfl_xor(d0, d); d1 += __shfl_xor(d1, d);
      d2 += __shfl_xor(d2, d); d3 += __shfl_xor(d3, d);
    }
    sb[wv][lane] = s * (K * 2);
    wl[wv][lane] = valid ? make_float4(x0 / (d0 + 1e-16f), x1 / (d1 + 1e-16f),
                                       x2 / (d2 + 1e-16f), x3 / (d3 + 1e-16f))
                         : make_float4(0.f, 0.f, 0.f, 0.f);
    __builtin_amdgcn_wave_barrier();

    const int nb = (deg + 7) >> 3;  // >=1 (self-loop guarantees deg>=1)
    uint2 bA[8], bB[8];
    auto loadb = [&](int g, uint2* b) {
#pragma unroll
      for (int k = 0; k < 8; ++k) {
        const char* gp = fb + (size_t)sb[wv][g + k] + loff;
        if (KC == 4) b[k] = *(const uint2*)gp;
        else         b[k].x = *(const uint32_t*)gp;
      }
    };
    auto fmab = [&](int g, const uint2* b) {
#pragma unroll
      for (int k = 0; k < 8; ++k) {
        const float4 w = wl[wv][g + k];
        if (KC == 4) {
          float v0 = bflo(b[k].x), v1 = bfhi(b[k].x), v2 = bflo(b[k].y), v3 = bfhi(b[k].y);
          acc[0][0] += w.x * v0; acc[0][1] += w.x * v1; acc[0][2] += w.x * v2; acc[0][3] += w.x * v3;
          acc[1][0] += w.y * v0; acc[1][1] += w.y * v1; acc[1][2] += w.y * v2; acc[1][3] += w.y * v3;
          acc[2][0] += w.z * v0; acc[2][1] += w.z * v1; acc[2][2] += w.z * v2; acc[2][3] += w.z * v3;
          acc[3][0] += w.w * v0; acc[3][1] += w.w * v1; acc[3][2] += w.w * v2; acc[3][3] += w.w * v3;
        } else {
          float v0 = bflo(b[k].x), v1 = bfhi(b[k].x);
          acc[0][0] += w.x * v0; acc[0][1] += w.x * v1;
          acc[1][0] += w.y * v0; acc[1][1] += w.y * v1;
          acc[2][0] += w.z * v0; acc[2][1] += w.z * v1;
          acc[3][0] += w.w * v0; acc[3][1] += w.w * v1;
        }
      }
    };
    loadb(0, bA);
    int i = 0;
    while (i + 2 <= nb) {
      loadb((i + 1) * 8, bB);
      fmab(i * 8, bA);
      if (i + 2 < nb) loadb((i + 2) * 8, bA);
      fmab((i + 1) * 8, bB);
      i += 2;
    }
    if (i < nb) fmab(i * 8, bA);
  } else {
    float m0 = -1e30f, m1 = -1e30f, m2 = -1e30f, m3 = -1e30f;
    for (int i = r0 + lane; i < r1; i += 64) {
      const float4 av = *(const float4*)&asad[(size_t)col[i] * 8];
      m0 = fmaxf(m0, lrelu(av.x + adv.x)); m1 = fmaxf(m1, lrelu(av.y + adv.y));
      m2 = fmaxf(m2, lrelu(av.z + adv.z)); m3 = fmaxf(m3, lrelu(av.w + adv.w));
    }
#pragma unroll
    for (int d = 1; d < 64; d <<= 1) {
      m0 = fmaxf(m0, __shfl_xor(m0, d)); m1 = fmaxf(m1, __shfl_xor(m1, d));
      m2 = fmaxf(m2, __shfl_xor(m2, d)); m3 = fmaxf(m3, __shfl_xor(m3, d));
    }
    float d0 = 0.f, d1 = 0.f, d2 = 0.f, d3 = 0.f;
    for (int i = r0 + lane; i < r1; i += 64) {
      const float4 av = *(const float4*)&asad[(size_t)col[i] * 8];
      d0 += __expf(lrelu(av.x + adv.x) - m0); d1 += __expf(lrelu(av.y + adv.y) - m1);
      d2 += __expf(lrelu(av.z + adv.z) - m2); d3 += __expf(lrelu(av.w + adv.w) - m3);
    }
#pragma unroll
    for (int d = 1; d < 64; d <<= 1) {
      d0 += __shfl_xor(d0, d); d1 += __shfl_xor(d1, d);
      d2 += __shfl_xor(d2, d); d3 += __shfl_xor(d3, d);
    }
    const float i0 = 1.f / (d0 + 1e-16f), i1 = 1.f / (d1 + 1e-16f);
    const float i2 = 1.f / (d2 + 1e-16f), i3 = 1.f / (d3 + 1e-16f);
    for (int base = r0; base < r1; base += 64) {
      const int ne = min(64, r1 - base);
      if (lane < ne) {
        const int s = col[base + lane];
        const float4 av = *(const float4*)&asad[(size_t)s * 8];
        sb[wv][lane] = s * (K * 2);
        wl[wv][lane] = make_float4(__expf(lrelu(av.x + adv.x) - m0) * i0,
                                   __expf(lrelu(av.y + adv.y) - m1) * i1,
                                   __expf(lrelu(av.z + adv.z) - m2) * i2,
                                   __expf(lrelu(av.w + adv.w) - m3) * i3);
      }
      __builtin_amdgcn_wave_barrier();
      for (int g = 0; g < ne; ++g)
        edge_fma(fb + (size_t)sb[wv][g] + loff, wl[wv][g]);
      __builtin_amdgcn_wave_barrier();
    }
  }

#pragma unroll
  for (int j = 0; j < 4; ++j) {
    if (KC == 4) {
      uint2 ov;
      ov.x = pack2bf(acc[j][0], acc[j][1]);
      ov.y = pack2bf(acc[j][2], acc[j][3]);
      *(uint2*)&agg[(size_t)n * (4 * K) + j * K + lane * 4] = ov;
    } else {
      *(uint32_t*)&agg[(size_t)n * (4 * K) + j * K + lane * 2] = pack2bf(acc[j][0], acc[j][1]);
    }
  }
}

// ---------------- input-space GAT aggregation, H=1 (K=128): 2 nodes/block ------------

__global__ __launch_bounds__(128) void gat_agg_in1(const bf16_t* __restrict__ f,
                                                   const float* __restrict__ asad,
                                                   const int* __restrict__ cnt,
                                                   const int* __restrict__ col,
                                                   bf16_t* __restrict__ agg) {
  const int wv = threadIdx.x >> 6, lane = threadIdx.x & 63;
  const int n = blockIdx.x * 2 + wv;
  __shared__ int sb[2][64];
  __shared__ float wl[2][64];

  const int r0 = n * CAP;
  const int deg = cnt[n];
  const int r1 = r0 + deg;
  const float adv = asad[(size_t)n * 2 + 1];
  const char* fb = (const char*)f;
  const size_t loff = (size_t)lane * 4;
  float a0 = 0.f, a1 = 0.f;

  auto fma2 = [&](uint32_t v, float w) { a0 += w * bflo(v); a1 += w * bfhi(v); };

  if (deg <= 64) {
    const bool valid = lane < deg;
    int s = n;  // invalid lanes: self row, weight 0
    float e = -1e30f;
    if (valid) { s = col[r0 + lane]; e = lrelu(asad[(size_t)s * 2] + adv); }
    float m = e;
#pragma unroll
    for (int d = 1; d < 64; d <<= 1) m = fmaxf(m, __shfl_xor(m, d));
    float x = valid ? __expf(e - m) : 0.f;
    float den = x;
#pragma unroll
    for (int d = 1; d < 64; d <<= 1) den += __shfl_xor(den, d);
    sb[wv][lane] = s * 256;
    wl[wv][lane] = valid ? x / (den + 1e-16f) : 0.f;
    __builtin_amdgcn_wave_barrier();

    const int nb = (deg + 7) >> 3;
    uint32_t bA[8], bB[8];
    auto loadb = [&](int g, uint32_t* b) {
#pragma unroll
      for (int k = 0; k < 8; ++k)
        b[k] = *(const uint32_t*)(fb + (size_t)sb[wv][g + k] + loff);
    };
    auto fmab = [&](int g, const uint32_t* b) {
#pragma unroll
      for (int k = 0; k < 8; ++k) {
        const float w = wl[wv][g + k];
        a0 += w * bflo(b[k]); a1 += w * bfhi(b[k]);
      }
    };
    loadb(0, bA);
    int i = 0;
    while (i + 2 <= nb) {
      loadb((i + 1) * 8, bB);
      fmab(i * 8, bA);
      if (i + 2 < nb) loadb((i + 2) * 8, bA);
      fmab((i + 1) * 8, bB);
      i += 2;
    }
    if (i < nb) fmab(i * 8, bA);
  } else {
    float m = -1e30f;
    for (int i = r0 + lane; i < r1; i += 64) m = fmaxf(m, lrelu(asad[(size_t)col[i] * 2] + adv));
#pragma unroll
    for (int d = 1; d < 64; d <<= 1) m = fmaxf(m, __shfl_xor(m, d));
    float den = 0.f;
    for (int i = r0 + lane; i < r1; i += 64) den += __expf(lrelu(asad[(size_t)col[i] * 2] + adv) - m);
#pragma unroll
    for (int d = 1; d < 64; d <<= 1) den += __shfl_xor(den, d);
    const float dinv = 1.f / (den + 1e-16f);
    for (int base = r0; base < r1; base += 64) {
      const int ne = min(64, r1 - base);
      if (lane < ne) {
        const int s = col[base + lane];
        sb[wv][lane] = s * 256;
        wl[wv][lane] = __expf(lrelu(asad[(size_t)s * 2] + adv) - m) * dinv;
      }
      __builtin_amdgcn_wave_barrier();
      for (int g = 0; g < ne; ++g)
        fma2(*(const uint32_t*)(fb + (size_t)sb[wv][g] + loff), wl[wv][g]);
      __builtin_amdgcn_wave_barrier();
    }
  }
  *(uint32_t*)&agg[(size_t)n * 128 + lane * 2] = pack2bf(a0, a1);
}

// ---------------- fused classifier tail (FROZEN: exact known-pass bytes) ----------------
// Empirically threshold-sensitive to restructuring (R7/R8 failures) -> do not modify.

__global__ __launch_bounds__(256) void mlp_tail(const bf16_t* __restrict__ A,
                                                const bf16_t* __restrict__ M3t,
                                                const float* __restrict__ bm,
                                                const bf16_t* __restrict__ l2t,
                                                const float* __restrict__ l2b,
                                                const bf16_t* __restrict__ l3t,
                                                const float* __restrict__ l3b,
                                                float* __restrict__ out, int M) {
  __shared__ __align__(16) bf16_t As[128 * 128];
  __shared__ __align__(16) bf16_t Ws[128 * 128];
  const int t = threadIdx.x, wave = t >> 6, lane = t & 63;
  const int ln15 = lane & 15, quad = lane >> 4;
  const int bmr = blockIdx.x * 128;
  const int rowLim = M - 1 - bmr;

#pragma unroll
  for (int r = 0; r < 8; ++r) {
    int base = (wave * 8 + r) * 1024;
    int flat = base + lane * 16;
    int row = flat >> 8;
    int grow = row < rowLim ? row : rowLim;
    const char* gp = (const char*)A + (size_t)grow * 256 + (flat & 255);
    __builtin_amdgcn_global_load_lds((const AS1 void*)gp,
                                     (AS3 void*)((char*)As + base), 16, 0, 0);
  }
#pragma unroll
  for (int r = 0; r < 8; ++r) {
    int base = (wave * 8 + r) * 1024;
    __builtin_amdgcn_global_load_lds((const AS1 void*)((const char*)M3t + base + lane * 16),
                                     (AS3 void*)((char*)Ws + base), 16, 0, 0);
  }
  __syncthreads();

  const int wm = wave * 32;
  f32x4 a1[2][8];
#pragma unroll
  for (int mi = 0; mi < 2; ++mi)
#pragma unroll
    for (int ni = 0; ni < 8; ++ni) a1[mi][ni] = (f32x4){0.f, 0.f, 0.f, 0.f};
#pragma unroll
  for (int kk = 0; kk < 128; kk += 32) {
    bf16x8 af[2];
#pragma unroll
    for (int mi = 0; mi < 2; ++mi)
      af[mi] = *(const bf16x8*)&As[(wm + mi * 16 + ln15) * 128 + kk + quad * 8];
#pragma unroll
    for (int ni = 0; ni < 8; ++ni) {
      bf16x8 bf = *(const bf16x8*)&Ws[(ni * 16 + ln15) * 128 + kk + quad * 8];
#pragma unroll
      for (int mi = 0; mi < 2; ++mi)
        a1[mi][ni] = __builtin_amdgcn_mfma_f32_16x16x32_bf16(af[mi], bf, a1[mi][ni], 0, 0, 0);
    }
  }
  __syncthreads();

#pragma unroll
  for (int r = 0; r < 4; ++r) {
    int base = (wave * 4 + r) * 1024;
    __builtin_amdgcn_global_load_lds((const AS1 void*)((const char*)l2t + base + lane * 16),
                                     (AS3 void*)((char*)Ws + base), 16, 0, 0);
  }
#pragma unroll
  for (int r = 0; r < 2; ++r) {
    int base = (wave * 2 + r) * 1024;
    __builtin_amdgcn_global_load_lds((const AS1 void*)((const char*)l3t + base + lane * 16),
                                     (AS3 void*)((char*)Ws + 8192 * 2 + base), 16, 0, 0);
  }
#pragma unroll
  for (int mi = 0; mi < 2; ++mi) {
    int r0 = wm + mi * 16 + quad * 4;
#pragma unroll
    for (int ni = 0; ni < 8; ++ni) {
      int c = ni * 16 + ln15;
      float bv = bm[c];
#pragma unroll
      for (int reg = 0; reg < 4; ++reg)
        As[(r0 + reg) * 128 + c] = (bf16_t)fmaxf(a1[mi][ni][reg] + bv, 0.f);
    }
  }
  __syncthreads();

  f32x4 a2[2][4];
#pragma unroll
  for (int mi = 0; mi < 2; ++mi)
#pragma unroll
    for (int ni = 0; ni < 4; ++ni) a2[mi][ni] = (f32x4){0.f, 0.f, 0.f, 0.f};
#pragma unroll
  for (int kk = 0; kk < 128; kk += 32) {
    bf16x8 af[2];
#pragma unroll
    for (int mi = 0; mi < 2; ++mi)
      af[mi] = *(const bf16x8*)&As[(wm + mi * 16 + ln15) * 128 + kk + quad * 8];
#pragma unroll
    for (int ni = 0; ni < 4; ++ni) {
      bf16x8 bf = *(const bf16x8*)&Ws[(ni * 16 + ln15) * 128 + kk + quad * 8];
#pragma unroll
      for (int mi = 0; mi < 2; ++mi)
        a2[mi][ni] = __builtin_amdgcn_mfma_f32_16x16x32_bf16(af[mi], bf, a2[mi][ni], 0, 0, 0);
    }
  }
  __syncthreads();

#pragma unroll
  for (int mi = 0; mi < 2; ++mi) {
    int r0 = wm + mi * 16 + quad * 4;
#pragma unroll
    for (int ni = 0; ni < 4; ++ni) {
      int c = ni * 16 + ln15;
      float bv = l2b[c];
#pragma unroll
      for (int reg = 0; reg < 4; ++reg)
        As[(r0 + reg) * 64 + c] = (bf16_t)fmaxf(a2[mi][ni][reg] + bv, 0.f);
    }
  }
  __syncthreads();

  f32x4 a3[2][4];
#pragma unroll
  for (int mi = 0; mi < 2; ++mi)
#pragma unroll
    for (int ni = 0; ni < 4; ++ni) a3[mi][ni] = (f32x4){0.f, 0.f, 0.f, 0.f};
#pragma unroll
  for (int kk = 0; kk < 64; kk += 32) {
    bf16x8 af[2];
#pragma unroll
    for (int mi = 0; mi < 2; ++mi)
      af[mi] = *(const bf16x8*)&As[(wm + mi * 16 + ln15) * 64 + kk + quad * 8];
#pragma unroll
    for (int ni = 0; ni < 4; ++ni) {
      bf16x8 bf = *(const bf16x8*)&Ws[8192 + (ni * 16 + ln15) * 64 + kk + quad * 8];
#pragma unroll
      for (int mi = 0; mi < 2; ++mi)
        a3[mi][ni] = __builtin_amdgcn_mfma_f32_16x16x32_bf16(af[mi], bf, a3[mi][ni], 0, 0, 0);
    }
  }
#pragma unroll
  for (int mi = 0; mi < 2; ++mi) {
    int r0 = wm + mi * 16 + quad * 4;
#pragma unroll
    for (int ni = 0; ni < 4; ++ni) {
      int c = ni * 16 + ln15;
      float bv = l3b[c];
#pragma unroll
      for (int reg = 0; reg < 4; ++reg) {
        int r = bmr + r0 + reg;
        if (r < M) {
          float v = a3[mi][ni][reg] + bv;
          out[(size_t)r * 64 + c] = 1.f / (1.f + __expf(-v));
        }
      }
    }
  }
}

// ---------------- launch ----------------

extern "C" void kernel_launch(void* const* d_in, const int* in_sizes, int n_in,
                              void* d_out, int out_size, void* d_ws, size_t ws_size,
                              hipStream_t stream) {
  const float* x      = (const float*)d_in[0];
  const int*   ei     = (const int*)d_in[1];
  const float* W1     = (const float*)d_in[2];
  const float* a_src1 = (const float*)d_in[3];
  const float* a_dst1 = (const float*)d_in[4];
  const float* b1     = (const float*)d_in[5];
  const float* W2     = (const float*)d_in[6];
  const float* a_src2 = (const float*)d_in[7];
  const float* a_dst2 = (const float*)d_in[8];
  const float* b2     = (const float*)d_in[9];
  const float* W3     = (const float*)d_in[10];
  const float* a_src3 = (const float*)d_in[11];
  const float* a_dst3 = (const float*)d_in[12];
  const float* b3     = (const float*)d_in[13];
  const float* bn1g = (const float*)d_in[14];
  const float* bn1b = (const float*)d_in[15];
  const float* bn1m = (const float*)d_in[16];
  const float* bn1v = (const float*)d_in[17];
  const float* bn2g = (const float*)d_in[18];
  const float* bn2b = (const float*)d_in[19];
  const float* bn2m = (const float*)d_in[20];
  const float* bn2v = (const float*)d_in[21];
  const float* l1w = (const float*)d_in[22];
  const float* l1b = (const float*)d_in[23];
  const float* l2w = (const float*)d_in[24];
  const float* l2b = (const float*)d_in[25];
  const float* l3w = (const float*)d_in[26];
  const float* l3b = (const float*)d_in[27];
  float* out = (float*)d_out;

  const int N = NN;
  const int E = in_sizes[1] / 2;
  const int ET = E + N;
  const int EB = (ET + 255) / 256;

  char* p = (char*)d_ws;
  auto carve = [&](size_t bytes) {
    char* q = p;
    p += (bytes + 255) & ~(size_t)255;
    return q;
  };
  bf16_t* xb    = (bf16_t*)carve((size_t)N * 256 * 2);
  bf16_t* aggb  = (bf16_t*)carve((size_t)N * 1024 * 2);
  bf16_t* f1b   = (bf16_t*)carve((size_t)N * 128 * 2);
  bf16_t* f2b   = (bf16_t*)carve((size_t)N * 128 * 2);
  float* asadA  = (float*)carve((size_t)N * 8 * 4);
  int* cnt      = (int*)carve((size_t)N * 4);
  // asadB/asadC now fully written by gemm plain stores (no memset needed)
  float* asadB  = (float*)carve((size_t)N * 8 * 4);
  float* asadC  = (float*)carve((size_t)N * 2 * 4);
  int* col      = (int*)carve((size_t)N * CAP * 4);
  bf16_t* Ws1t  = (bf16_t*)carve((size_t)128 * 1024 * 2);
  bf16_t* Ws2t  = (bf16_t*)carve((size_t)128 * 512 * 2);
  bf16_t* M3t   = (bf16_t*)carve((size_t)128 * 128 * 2);
  bf16_t* l2t   = (bf16_t*)carve((size_t)64 * 128 * 2);
  bf16_t* l3t   = (bf16_t*)carve((size_t)64 * 64 * 2);
  float* P1     = (float*)carve((size_t)8 * 256 * 4);
  float* P2     = (float*)carve((size_t)8 * 128 * 4);
  float* P3     = (float*)carve((size_t)2 * 128 * 4);
  float* bm     = (float*)carve((size_t)128 * 4);
  (void)ws_size; (void)n_in; (void)out_size;

  hipMemsetAsync(cnt, 0, (size_t)N * 4, stream);

  Prep1Args pa;
  pa.wp.d[0] = {W1,  Ws1t, 256, 128, 4, 0.25f, 0};
  pa.wp.d[1] = {W2,  Ws2t, 128, 128, 4, 0.25f, 128};
  pa.wp.d[2] = {l2w, l2t,  128, 64,  1, 1.0f,  192};
  pa.wp.d[3] = {l3w, l3t,  64,  64,  1, 1.0f,  200};
  pa.W1 = W1; pa.as1 = a_src1; pa.ad1 = a_dst1;
  pa.W2 = W2; pa.as2 = a_src2; pa.ad2 = a_dst2;
  pa.W3 = W3; pa.as3 = a_src3; pa.ad3 = a_dst3;
  pa.P1 = P1; pa.P2 = P2; pa.P3 = P3;
  pa.W3m = W3; pa.L1w = l1w; pa.b3v = b3; pa.l1b = l1b;
  pa.M3t = M3t; pa.bm = bm;
  pa.ei = ei; pa.E = E; pa.N = N; pa.EB = EB;
  pa.cnt = cnt; pa.col = col;
  prep1<<<780 + EB, 256, 0, stream>>>(pa);

  // separate launch: consumes P1 produced by prep1 (kernel boundary = ordering)
  cast_alpha<<<N / 4, 256, 0, stream>>>(x, P1, xb, asadA);

  const int gm32 = (N + 31) / 32;   // 625 row-tiles for the TM=32 GEMM
  const int gm   = (N + 127) / 128; // 157 row-tiles for mlp_tail
  const int gb   = N / 2;           // 10000 gather blocks (2 nodes each)

  // --- GAT layer 1 (GEMM epilogue also emits layer-2 alpha logits) ---
  gat_agg_in4<256><<<gb, 128, 0, stream>>>(xb, asadA, cnt, col, aggb);
  gemm_mfma<3, 8, bf16_t><<<dim3(gm32, 1), 256, 0, stream>>>(
      aggb, Ws1t, b1, bn1g, bn1b, bn1m, bn1v, f1b, P2, asadB, N, 128, 1024);

  // --- GAT layer 2 (GEMM epilogue emits layer-3 alpha logits) ---
  gat_agg_in4<128><<<gb, 128, 0, stream>>>(f1b, asadB, cnt, col, aggb);
  gemm_mfma<3, 2, bf16_t><<<dim3(gm32, 1), 256, 0, stream>>>(
      aggb, Ws2t, b2, bn2g, bn2b, bn2m, bn2v, f2b, P3, asadC, N, 128, 512);

  // --- GAT layer 3 (H=1) + fused classifier tail ---
  gat_agg_in1<<<gb, 128, 0, stream>>>(f2b, asadC, cnt, col, aggb);
  mlp_tail<<<gm, 256, 0, stream>>>(aggb, M3t, bm, l2t, l2b, l3t, l3b, out, N);
}